// Round 11
// baseline (1227.387 us; speedup 1.0000x reference)
//
#include <hip/hip_runtime.h>
#include <hip/hip_bf16.h>

#define NN 50000
#define EE 800000
#define NE 850000       // edges + self-loops
#define HID 128
#define NEG_SLOPE 0.2f
#define EPSN 1e-5f
#define NB 196          // buckets of 256 nodes
#define BCAP 6144       // bucket capacity (expected 4352 +- 64)
#define TB 4096         // edges per k_bin block
#define REP 16          // GraphNorm stats replicas (double-buffered)
#define NPS 4           // nodes per slot in k_gat_node

typedef __attribute__((ext_vector_type(8))) short bf16x8;
typedef __attribute__((ext_vector_type(4))) float f32x4;

__device__ __forceinline__ unsigned short f2b(float f) {
    unsigned u = __float_as_uint(f);
    unsigned r = (u + 0x7FFFu + ((u >> 16) & 1u)) >> 16;
    return (unsigned short)r;
}
__device__ __forceinline__ float b2f(unsigned short u) {
    return __uint_as_float(((unsigned)u) << 16);
}
__device__ __forceinline__ float2 up2(unsigned u) {
    return make_float2(__uint_as_float(u << 16),
                       __uint_as_float(u & 0xFFFF0000u));
}
__device__ __forceinline__ float2 pk_fma(float2 a, float2 b, float2 c) {
    return make_float2(fmaf(a.x, b.x, c.x), fmaf(a.y, b.y, c.y));
}
__device__ __forceinline__ float2 pk_add(float2 a, float2 b) {
    return make_float2(a.x + b.x, a.y + b.y);
}
__device__ __forceinline__ float2 pk_leaky(float2 v) {
    return make_float2(fmaxf(v.x, NEG_SLOPE * v.x), fmaxf(v.y, NEG_SLOPE * v.y));
}

// ---------------- prep: W->bf16^T, x->bf16, zero bcnt + both stats buffers ----------------
__global__ void k_prep(const float* __restrict__ x, const float* __restrict__ Wl,
                       const float* __restrict__ Wr, const float* __restrict__ skip_W,
                       unsigned short* __restrict__ xb, unsigned short* __restrict__ wt,
                       unsigned short* __restrict__ st, int* __restrict__ bcnt,
                       float* __restrict__ stats) {
    int i = blockIdx.x * blockDim.x + threadIdx.x;
    if (i < NN * HID / 4) {
        float4 v = *(const float4*)&x[i * 4];
        ushort4 o = {f2b(v.x), f2b(v.y), f2b(v.z), f2b(v.w)};
        *(ushort4*)&xb[i * 4] = o;
    }
    if (i < NB) bcnt[i] = 0;
    if (i < 2 * REP * 256) stats[i] = 0.f;
    if (i < 4 * 256 * 128) {
        int l = i >> 15, rem = i & 32767;
        int c = rem >> 7, k = rem & 127;
        float v = (c < 128) ? Wl[l * 16384 + k * 128 + c]
                            : Wr[l * 16384 + k * 128 + (c - 128)];
        wt[i] = f2b(v);
    } else if (i < 4 * 256 * 128 + 128 * 128) {
        int j = i - 4 * 256 * 128;
        int c = j >> 7, k = j & 127;
        st[j] = f2b(skip_W[k * 128 + c]);
    }
}

// ---------------- CSR build: bucket sort ----------------
__global__ void __launch_bounds__(256) k_bin(const int* __restrict__ ei,
                                             int* __restrict__ bcnt,
                                             unsigned* __restrict__ bbuf) {
    __shared__ int hist[NB];
    __shared__ int gbase[NB];
    int t = threadIdx.x;
    for (int b = t; b < NB; b += 256) hist[b] = 0;
    __syncthreads();
    int e0 = blockIdx.x * TB;
    unsigned ent[16];
    int bkt[16];
#pragma unroll
    for (int k = 0; k < 16; k++) {
        int e = e0 + k * 256 + t;
        if (e < NE) {
            int src, dst;
            if (e < EE) { src = ei[e]; dst = ei[EE + e]; }
            else        { src = e - EE; dst = src; }
            int b = dst >> 8;
            ent[k] = ((unsigned)(dst & 255) << 17) | (unsigned)src;
            bkt[k] = b;
            atomicAdd(&hist[b], 1);
        } else bkt[k] = -1;
    }
    __syncthreads();
    for (int b = t; b < NB; b += 256) {
        int c = hist[b];
        gbase[b] = (c > 0) ? atomicAdd(&bcnt[b], c) : 0;
        hist[b] = 0;
    }
    __syncthreads();
#pragma unroll
    for (int k = 0; k < 16; k++) {
        int b = bkt[k];
        if (b >= 0) {
            int pos = gbase[b] + atomicAdd(&hist[b], 1);
            if (pos < BCAP) bbuf[(size_t)b * BCAP + pos] = ent[k];
        }
    }
}

// Per-bucket CSR: inline prefix scan of bucket counts (replaces k_scan_b),
// per-node offsets, coalesced row_ptr, local scatter. csr stores BYTE offsets
// (src*512) into xlr.
__global__ void __launch_bounds__(256) k_bucket_csr(
    const unsigned* __restrict__ bbuf, const int* __restrict__ bcnt,
    int* __restrict__ row_ptr, int* __restrict__ csr_off) {
    __shared__ unsigned se[BCAP];
    __shared__ int pre[256];
    __shared__ int hist[256], scn[256], exs[256], cur[256];
    int b = blockIdx.x, t = threadIdx.x;
    int bv = (t < NB) ? bcnt[t] : 0;
    pre[t] = bv;
    __syncthreads();
    for (int o = 1; o < 256; o <<= 1) {
        int u = (t >= o) ? pre[t - o] : 0;
        __syncthreads();
        pre[t] += u;
        __syncthreads();
    }
    int cntb = bcnt[b];
    int base = pre[b] - cntb;          // exclusive prefix
    int cnt = min(cntb, BCAP);
    hist[t] = 0;
    cur[t] = 0;
    __syncthreads();
    for (int j = t; j < cnt; j += 256) {
        unsigned e = bbuf[(size_t)b * BCAP + j];
        se[j] = e;
        atomicAdd(&hist[e >> 17], 1);
    }
    __syncthreads();
    int v = hist[t];
    scn[t] = v;
    __syncthreads();
    for (int o = 1; o < 256; o <<= 1) {
        int u = (t >= o) ? scn[t - o] : 0;
        __syncthreads();
        scn[t] += u;
        __syncthreads();
    }
    int ex = scn[t] - v;
    exs[t] = ex;
    int node = b * 256 + t;
    if (node < NN) row_ptr[node] = base + ex;
    if (b == NB - 1 && t == 0) row_ptr[NN] = NE;
    __syncthreads();
    for (int j = t; j < cnt; j += 256) {
        unsigned e = se[j];
        int dl = e >> 17;
        int p = exs[dl] + atomicAdd(&cur[dl], 1);
        csr_off[base + p] = (int)((e & 0x1FFFFu) << 9);   // src * 512 bytes
    }
}

// ---------------- MFMA GEMM: xlr[N,256](bf16) = Xb[N,128] @ Wcat[128,256] ----------------
__global__ void __launch_bounds__(256) k_gemm_dual_mfma(
    const unsigned short* __restrict__ Xb, const unsigned short* __restrict__ WT,
    unsigned short* __restrict__ C) {
    int w = threadIdx.x >> 6, lane = threadIdx.x & 63;
    int quad = lane >> 4, l16 = lane & 15;
    int r0 = blockIdx.x * 64 + w * 16;
    int lrow = r0 + l16; if (lrow >= NN) lrow = NN - 1;
    const unsigned short* arow = Xb + (size_t)lrow * 128 + quad * 8;
    bf16x8 a[4];
#pragma unroll
    for (int ks = 0; ks < 4; ks++) a[ks] = *(const bf16x8*)(arow + ks * 32);
    f32x4 acc[16];
#pragma unroll
    for (int ct = 0; ct < 16; ct++) acc[ct] = (f32x4){0, 0, 0, 0};
#pragma unroll
    for (int ct = 0; ct < 16; ct++) {
        const unsigned short* bbase = WT + (size_t)(ct * 16 + l16) * 128 + quad * 8;
#pragma unroll
        for (int ks = 0; ks < 4; ks++) {
            bf16x8 b = *(const bf16x8*)(bbase + ks * 32);
            acc[ct] = __builtin_amdgcn_mfma_f32_16x16x32_bf16(a[ks], b, acc[ct], 0, 0, 0);
        }
    }
    int sr = r0 + quad * 4;
#pragma unroll
    for (int ct = 0; ct < 16; ct++) {
#pragma unroll
        for (int r = 0; r < 4; r++) {
            int rr = sr + r;
            if (rr < NN) C[(size_t)rr * 256 + ct * 16 + l16] = f2b(acc[ct][r]);
        }
    }
}

// ---------------- MFMA GEMM skip + inline GraphNorm finalize ----------------
// Each block reduces the REP stats replicas -> scoff in LDS, then
// Xb16 += ELU(norm(h)) @ skipW + b  (all bf16).
__global__ void __launch_bounds__(256) k_gemm_skip_mfma(
    const unsigned short* __restrict__ hbufb, const float* __restrict__ stats,
    const float* __restrict__ gn_w, const float* __restrict__ gn_b,
    const float* __restrict__ gn_ms, const unsigned short* __restrict__ ST,
    const float* __restrict__ skip_b, unsigned short* __restrict__ Xb16) {
    __shared__ float tot[256];
    __shared__ float scoff_s[256];
    int t = threadIdx.x;
    float s = 0.f;
#pragma unroll
    for (int r = 0; r < REP; r++) s += stats[r * 256 + t];
    tot[t] = s;
    __syncthreads();
    if (t < 128) {
        const float invN = 1.0f / (float)NN;
        float mean = tot[t] * invN;
        float ex2 = tot[128 + t] * invN;
        float ms = gn_ms[t];
        float var = ex2 - (2.f * ms - ms * ms) * mean * mean;
        float wsc = gn_w[t] * rsqrtf(var + EPSN);
        scoff_s[t] = wsc;
        scoff_s[128 + t] = gn_b[t] - wsc * ms * mean;
    }
    __syncthreads();
    int w = t >> 6, lane = t & 63;
    int quad = lane >> 4, l16 = lane & 15;
    int r0 = blockIdx.x * 64 + w * 16;
    int c0 = blockIdx.y * 64;
    int lrow = r0 + l16; if (lrow >= NN) lrow = NN - 1;
    const unsigned short* hrow = hbufb + (size_t)lrow * 128 + quad * 8;
    f32x4 acc0 = {0,0,0,0}, acc1 = {0,0,0,0}, acc2 = {0,0,0,0}, acc3 = {0,0,0,0};
#pragma unroll
    for (int ks = 0; ks < 4; ks++) {
        int k0 = ks * 32;
        int kc = quad * 8 + k0;
        uint4 hw = *(const uint4*)(hrow + k0);
        float2 h01 = up2(hw.x), h23 = up2(hw.y), h45 = up2(hw.z), h67 = up2(hw.w);
        float4 sc0 = *(const float4*)&scoff_s[kc];
        float4 sc1 = *(const float4*)&scoff_s[kc + 4];
        float4 of0 = *(const float4*)&scoff_s[128 + kc];
        float4 of1 = *(const float4*)&scoff_s[128 + kc + 4];
        float e[8];
        e[0] = fmaf(sc0.x, h01.x, of0.x); e[1] = fmaf(sc0.y, h01.y, of0.y);
        e[2] = fmaf(sc0.z, h23.x, of0.z); e[3] = fmaf(sc0.w, h23.y, of0.w);
        e[4] = fmaf(sc1.x, h45.x, of1.x); e[5] = fmaf(sc1.y, h45.y, of1.y);
        e[6] = fmaf(sc1.z, h67.x, of1.z); e[7] = fmaf(sc1.w, h67.y, of1.w);
        bf16x8 a;
#pragma unroll
        for (int j = 0; j < 8; j++) {
            float v = e[j];
            v = (v > 0.f) ? v : (__expf(v) - 1.f);
            a[j] = (short)f2b(v);
        }
        const unsigned short* bbase = ST + (size_t)(c0 + l16) * 128 + quad * 8 + k0;
        bf16x8 b0 = *(const bf16x8*)(bbase);
        bf16x8 b1 = *(const bf16x8*)(bbase + 16 * 128);
        bf16x8 b2 = *(const bf16x8*)(bbase + 32 * 128);
        bf16x8 b3 = *(const bf16x8*)(bbase + 48 * 128);
        acc0 = __builtin_amdgcn_mfma_f32_16x16x32_bf16(a, b0, acc0, 0, 0, 0);
        acc1 = __builtin_amdgcn_mfma_f32_16x16x32_bf16(a, b1, acc1, 0, 0, 0);
        acc2 = __builtin_amdgcn_mfma_f32_16x16x32_bf16(a, b2, acc2, 0, 0, 0);
        acc3 = __builtin_amdgcn_mfma_f32_16x16x32_bf16(a, b3, acc3, 0, 0, 0);
    }
    float sb0 = skip_b[c0 + l16];
    float sb1 = skip_b[c0 + 16 + l16];
    float sb2 = skip_b[c0 + 32 + l16];
    float sb3 = skip_b[c0 + 48 + l16];
    int sr = r0 + quad * 4;
#pragma unroll
    for (int r = 0; r < 4; r++) {
        int rr = sr + r;
        if (rr < NN) {
            size_t base = (size_t)rr * 128 + c0 + l16;
            float v0 = b2f(Xb16[base])      + acc0[r] + sb0;
            float v1 = b2f(Xb16[base + 16]) + acc1[r] + sb1;
            float v2 = b2f(Xb16[base + 32]) + acc2[r] + sb2;
            float v3 = b2f(Xb16[base + 48]) + acc3[r] + sb3;
            Xb16[base]      = f2b(v0);
            Xb16[base + 16] = f2b(v1);
            Xb16[base + 32] = f2b(v2);
            Xb16[base + 48] = f2b(v3);
        }
    }
}

// ---------------- fused GATv2: slot-owns-nodes, barrier-free ----------------
// 8 slots x 16 lanes per block; slot walks NPS consecutive nodes' contiguous
// (dst-sorted) edge range serially with depth-2 prefetch. No LDS, no barriers:
// channel accumulator stays in registers; head score = 2 shfls in 4-lane group.
// Stats pre-reduced in registers across NPS nodes -> 16 atomics/thread.
// First REP blocks also zero the OTHER layer-parity stats buffer.
__global__ void __launch_bounds__(128) k_gat_node(
    const unsigned short* __restrict__ xlr,
    const float* __restrict__ att, const float* __restrict__ conv_b,
    const int* __restrict__ row_ptr, const int* __restrict__ csr_off,
    unsigned short* __restrict__ houtb, float* __restrict__ stats_cur,
    float* __restrict__ stats_other) {
    int t = threadIdx.x;
    int slot = t >> 4, l = t & 15;
    if (blockIdx.x < REP) {
        stats_other[blockIdx.x * 256 + t] = 0.f;
        stats_other[blockIdx.x * 256 + 128 + t] = 0.f;
    }
    const char* xbytes = (const char*)xlr;
    float2 at2[4];
    float cb[8];
    {
        float4 a0 = *(const float4*)&att[8 * l];
        float4 a1 = *(const float4*)&att[8 * l + 4];
        at2[0] = make_float2(a0.x, a0.y); at2[1] = make_float2(a0.z, a0.w);
        at2[2] = make_float2(a1.x, a1.y); at2[3] = make_float2(a1.z, a1.w);
        float4 c0 = *(const float4*)&conv_b[8 * l];
        float4 c1 = *(const float4*)&conv_b[8 * l + 4];
        cb[0] = c0.x; cb[1] = c0.y; cb[2] = c0.z; cb[3] = c0.w;
        cb[4] = c1.x; cb[5] = c1.y; cb[6] = c1.z; cb[7] = c1.w;
    }
    float ssum[8], ssum2[8];
#pragma unroll
    for (int k = 0; k < 8; k++) { ssum[k] = 0.f; ssum2[k] = 0.f; }
    int s = blockIdx.x * 8 + slot;
    int n0 = s * NPS;
    if (n0 < NN) {
        int nEnd = min(n0 + NPS, NN);
        int curNode = n0;
        int curEnd = row_ptr[curNode + 1];
        int j = row_ptr[curNode];
        int jEndAll = row_ptr[nEnd];
        int lofs = 16 * l;
        uint4 xr_raw = *(const uint4*)(xbytes + (size_t)curNode * 512 + 256 + lofs);
        uint4 xrn = (curNode + 1 < nEnd)
            ? *(const uint4*)(xbytes + (size_t)(curNode + 1) * 512 + 256 + lofs)
            : (uint4){0, 0, 0, 0};
        float2 xr2[4];
        xr2[0] = up2(xr_raw.x); xr2[1] = up2(xr_raw.y);
        xr2[2] = up2(xr_raw.z); xr2[3] = up2(xr_raw.w);
        float den = 0.f;
        float2 acc[4];
#pragma unroll
        for (int k = 0; k < 4; k++) acc[k] = make_float2(0.f, 0.f);
        int o0 = csr_off[j];
        bool v1 = (j + 1) < jEndAll;
        int o1 = v1 ? csr_off[j + 1] : 0;
        uint4 w0 = *(const uint4*)(xbytes + (size_t)(unsigned)o0 + lofs);
        uint4 w1 = v1 ? *(const uint4*)(xbytes + (size_t)(unsigned)o1 + lofs)
                      : (uint4){0, 0, 0, 0};
        while (true) {
            bool v2 = (j + 2) < jEndAll;
            int o2 = v2 ? csr_off[j + 2] : 0;
            uint4 wp = v2 ? *(const uint4*)(xbytes + (size_t)(unsigned)o2 + lofs)
                          : (uint4){0, 0, 0, 0};
            float2 f0 = up2(w0.x), f1 = up2(w0.y), f2v = up2(w0.z), f3 = up2(w0.w);
            float2 ps = make_float2(0.f, 0.f);
            ps = pk_fma(at2[0], pk_leaky(pk_add(f0, xr2[0])), ps);
            ps = pk_fma(at2[1], pk_leaky(pk_add(f1, xr2[1])), ps);
            ps = pk_fma(at2[2], pk_leaky(pk_add(f2v, xr2[2])), ps);
            ps = pk_fma(at2[3], pk_leaky(pk_add(f3, xr2[3])), ps);
            float p = ps.x + ps.y;
            p += __shfl_xor(p, 1);       // 4-lane head group (32 ch/head)
            p += __shfl_xor(p, 2);
            float w = __expf(p);
            den += w;
            float2 wf = make_float2(w, w);
            acc[0] = pk_fma(wf, f0, acc[0]);
            acc[1] = pk_fma(wf, f1, acc[1]);
            acc[2] = pk_fma(wf, f2v, acc[2]);
            acc[3] = pk_fma(wf, f3, acc[3]);
            j++;
            if (j == curEnd) {           // node boundary: finalize in registers
                float inv = 1.f / den;
                float hv0 = fmaf(acc[0].x, inv, cb[0]);
                float hv1 = fmaf(acc[0].y, inv, cb[1]);
                float hv2 = fmaf(acc[1].x, inv, cb[2]);
                float hv3 = fmaf(acc[1].y, inv, cb[3]);
                float hv4 = fmaf(acc[2].x, inv, cb[4]);
                float hv5 = fmaf(acc[2].y, inv, cb[5]);
                float hv6 = fmaf(acc[3].x, inv, cb[6]);
                float hv7 = fmaf(acc[3].y, inv, cb[7]);
                uint4 ov;
                ov.x = (unsigned)f2b(hv0) | ((unsigned)f2b(hv1) << 16);
                ov.y = (unsigned)f2b(hv2) | ((unsigned)f2b(hv3) << 16);
                ov.z = (unsigned)f2b(hv4) | ((unsigned)f2b(hv5) << 16);
                ov.w = (unsigned)f2b(hv6) | ((unsigned)f2b(hv7) << 16);
                *(uint4*)&houtb[(size_t)curNode * 128 + 8 * l] = ov;
                ssum[0] += hv0; ssum2[0] += hv0 * hv0;
                ssum[1] += hv1; ssum2[1] += hv1 * hv1;
                ssum[2] += hv2; ssum2[2] += hv2 * hv2;
                ssum[3] += hv3; ssum2[3] += hv3 * hv3;
                ssum[4] += hv4; ssum2[4] += hv4 * hv4;
                ssum[5] += hv5; ssum2[5] += hv5 * hv5;
                ssum[6] += hv6; ssum2[6] += hv6 * hv6;
                ssum[7] += hv7; ssum2[7] += hv7 * hv7;
                curNode++;
                if (curNode >= nEnd) break;
                curEnd = row_ptr[curNode + 1];
                xr_raw = xrn;
                if (curNode + 1 < nEnd)
                    xrn = *(const uint4*)(xbytes + (size_t)(curNode + 1) * 512 + 256 + lofs);
                xr2[0] = up2(xr_raw.x); xr2[1] = up2(xr_raw.y);
                xr2[2] = up2(xr_raw.z); xr2[3] = up2(xr_raw.w);
                den = 0.f;
#pragma unroll
                for (int k = 0; k < 4; k++) acc[k] = make_float2(0.f, 0.f);
            }
            w0 = w1; w1 = wp;
        }
    }
    float* srep = stats_cur + (size_t)(blockIdx.x & (REP - 1)) * 256;
#pragma unroll
    for (int k = 0; k < 8; k++) {
        atomicAdd(&srep[8 * l + k], ssum[k]);
        atomicAdd(&srep[128 + 8 * l + k], ssum2[k]);
    }
}

// ---------------- final fc (bf16 x) ----------------
__global__ void __launch_bounds__(256) k_fc(const unsigned short* __restrict__ xb,
                                            const float* __restrict__ fc_W,
                                            const float* __restrict__ fc_b,
                                            float* __restrict__ out) {
    int t = threadIdx.x;
    int node = blockIdx.x * 4 + (t >> 6);
    int lane = t & 63;
    if (node >= NN) return;
    unsigned xu = *(const unsigned*)&xb[node * HID + lane * 2];
    float2 xv = up2(xu);
    float2 wv = *(const float2*)&fc_W[lane * 2];
    float p = xv.x * wv.x + xv.y * wv.y;
    p += __shfl_xor(p, 32);
    p += __shfl_xor(p, 16);
    p += __shfl_xor(p, 8);
    p += __shfl_xor(p, 4);
    p += __shfl_xor(p, 2);
    p += __shfl_xor(p, 1);
    if (lane == 0) out[node] = p + fc_b[0];
}

extern "C" void kernel_launch(void* const* d_in, const int* in_sizes, int n_in,
                              void* d_out, int out_size, void* d_ws, size_t ws_size,
                              hipStream_t stream) {
    const float* x_in   = (const float*)d_in[0];
    const int*   ei     = (const int*)d_in[1];
    const float* Wl     = (const float*)d_in[2];
    const float* Wr     = (const float*)d_in[3];
    const float* att    = (const float*)d_in[4];
    const float* conv_b = (const float*)d_in[5];
    const float* gn_w   = (const float*)d_in[6];
    const float* gn_b   = (const float*)d_in[7];
    const float* gn_ms  = (const float*)d_in[8];
    const float* skip_W = (const float*)d_in[9];
    const float* skip_b = (const float*)d_in[10];
    const float* fc_W   = (const float*)d_in[11];
    const float* fc_b   = (const float*)d_in[12];
    float* out = (float*)d_out;

    // workspace carve
    float* ws = (float*)d_ws;
    float* stats = ws;                              // 2 * REP * 256 (double-buffered)
    unsigned short* xlr   = (unsigned short*)(stats + 2 * REP * 256);  // N*256 bf16
    unsigned short* b16X  = xlr + (size_t)NN * 256; // N*HID bf16 (residual stream)
    unsigned short* hbufb = b16X + NN * HID;        // N*HID bf16
    unsigned short* wt    = hbufb + NN * HID;       // 4*256*128
    unsigned short* st    = wt + 4 * 256 * 128;     // 128*128
    int* row_ptr = (int*)(st + 128 * 128);          // N+1
    int* bcnt    = row_ptr + NN + 1;                // NB
    int* csr_off = bcnt + NB;                       // NE (byte offsets)
    unsigned* bbuf = (unsigned*)(csr_off + NE);     // NB*BCAP

    k_prep<<<(NN * HID / 4 + 255) / 256, 256, 0, stream>>>(
        x_in, Wl, Wr, skip_W, b16X, wt, st, bcnt, stats);

    // CSR build via bucket sort
    k_bin<<<(NE + TB - 1) / TB, 256, 0, stream>>>(ei, bcnt, bbuf);
    k_bucket_csr<<<NB, 256, 0, stream>>>(bbuf, bcnt, row_ptr, csr_off);

    const int rtiles = (NN + 63) / 64;                       // 782
    const int gat_blocks = (NN / NPS + 7) / 8 + 1;           // 1563 (slot-padded)
    for (int l = 0; l < 4; l++) {
        float* stats_cur   = stats + (size_t)(l & 1) * REP * 256;
        float* stats_other = stats + (size_t)((l + 1) & 1) * REP * 256;
        k_gemm_dual_mfma<<<rtiles, 256, 0, stream>>>(
            b16X, wt + (size_t)l * 256 * 128, xlr);
        k_gat_node<<<gat_blocks, 128, 0, stream>>>(
            xlr, att + l * HID, conv_b + l * HID, row_ptr, csr_off,
            hbufb, stats_cur, stats_other);
        k_gemm_skip_mfma<<<dim3(rtiles, 2), 256, 0, stream>>>(
            hbufb, stats_cur, gn_w + l * HID, gn_b + l * HID, gn_ms + l * HID,
            st, skip_b, b16X);
    }
    k_fc<<<(NN + 3) / 4, 256, 0, stream>>>(b16X, fc_W, fc_b, out);
}

// Round 12
// 757.363 us; speedup vs baseline: 1.6206x; 1.6206x over previous
//
#include <hip/hip_runtime.h>
#include <hip/hip_bf16.h>

#define NN 50000
#define EE 800000
#define NE 850000       // edges + self-loops
#define HID 128
#define NEG_SLOPE 0.2f
#define EPSN 1e-5f
#define NB 196          // buckets of 256 nodes
#define BCAP 6144       // bucket capacity (expected 4352 +- 64)
#define TB 4096         // edges per k_bin block
#define REP 32          // GraphNorm stats replicas (double-buffered)
#define NPW 8           // nodes per wave in k_gat_node

typedef __attribute__((ext_vector_type(8))) short bf16x8;
typedef __attribute__((ext_vector_type(4))) float f32x4;

__device__ __forceinline__ unsigned short f2b(float f) {
    unsigned u = __float_as_uint(f);
    unsigned r = (u + 0x7FFFu + ((u >> 16) & 1u)) >> 16;
    return (unsigned short)r;
}
__device__ __forceinline__ float b2f(unsigned short u) {
    return __uint_as_float(((unsigned)u) << 16);
}
__device__ __forceinline__ float2 up2(unsigned u) {
    return make_float2(__uint_as_float(u << 16),
                       __uint_as_float(u & 0xFFFF0000u));
}
__device__ __forceinline__ float2 pk_fma(float2 a, float2 b, float2 c) {
    return make_float2(fmaf(a.x, b.x, c.x), fmaf(a.y, b.y, c.y));
}
__device__ __forceinline__ float2 pk_add(float2 a, float2 b) {
    return make_float2(a.x + b.x, a.y + b.y);
}
__device__ __forceinline__ float2 pk_leaky(float2 v) {
    return make_float2(fmaxf(v.x, NEG_SLOPE * v.x), fmaxf(v.y, NEG_SLOPE * v.y));
}

// ---------------- prep: W->bf16^T, x->bf16, zero bcnt + both stats buffers ----------------
__global__ void k_prep(const float* __restrict__ x, const float* __restrict__ Wl,
                       const float* __restrict__ Wr, const float* __restrict__ skip_W,
                       unsigned short* __restrict__ xb, unsigned short* __restrict__ wt,
                       unsigned short* __restrict__ st, int* __restrict__ bcnt,
                       float* __restrict__ stats) {
    int i = blockIdx.x * blockDim.x + threadIdx.x;
    if (i < NN * HID / 4) {
        float4 v = *(const float4*)&x[i * 4];
        ushort4 o = {f2b(v.x), f2b(v.y), f2b(v.z), f2b(v.w)};
        *(ushort4*)&xb[i * 4] = o;
    }
    if (i < NB) bcnt[i] = 0;
    if (i < 2 * REP * 256) stats[i] = 0.f;
    if (i < 4 * 256 * 128) {
        int l = i >> 15, rem = i & 32767;
        int c = rem >> 7, k = rem & 127;
        float v = (c < 128) ? Wl[l * 16384 + k * 128 + c]
                            : Wr[l * 16384 + k * 128 + (c - 128)];
        wt[i] = f2b(v);
    } else if (i < 4 * 256 * 128 + 128 * 128) {
        int j = i - 4 * 256 * 128;
        int c = j >> 7, k = j & 127;
        st[j] = f2b(skip_W[k * 128 + c]);
    }
}

// ---------------- CSR build: bucket sort ----------------
__global__ void __launch_bounds__(256) k_bin(const int* __restrict__ ei,
                                             int* __restrict__ bcnt,
                                             unsigned* __restrict__ bbuf) {
    __shared__ int hist[NB];
    __shared__ int gbase[NB];
    int t = threadIdx.x;
    for (int b = t; b < NB; b += 256) hist[b] = 0;
    __syncthreads();
    int e0 = blockIdx.x * TB;
    unsigned ent[16];
    int bkt[16];
#pragma unroll
    for (int k = 0; k < 16; k++) {
        int e = e0 + k * 256 + t;
        if (e < NE) {
            int src, dst;
            if (e < EE) { src = ei[e]; dst = ei[EE + e]; }
            else        { src = e - EE; dst = src; }
            int b = dst >> 8;
            ent[k] = ((unsigned)(dst & 255) << 17) | (unsigned)src;
            bkt[k] = b;
            atomicAdd(&hist[b], 1);
        } else bkt[k] = -1;
    }
    __syncthreads();
    for (int b = t; b < NB; b += 256) {
        int c = hist[b];
        gbase[b] = (c > 0) ? atomicAdd(&bcnt[b], c) : 0;
        hist[b] = 0;
    }
    __syncthreads();
#pragma unroll
    for (int k = 0; k < 16; k++) {
        int b = bkt[k];
        if (b >= 0) {
            int pos = gbase[b] + atomicAdd(&hist[b], 1);
            if (pos < BCAP) bbuf[(size_t)b * BCAP + pos] = ent[k];
        }
    }
}

// Per-bucket CSR with inline prefix scan of bucket counts; csr stores BYTE
// offsets (src*512) into xlr.
__global__ void __launch_bounds__(256) k_bucket_csr(
    const unsigned* __restrict__ bbuf, const int* __restrict__ bcnt,
    int* __restrict__ row_ptr, int* __restrict__ csr_off) {
    __shared__ unsigned se[BCAP];
    __shared__ int pre[256];
    __shared__ int hist[256], scn[256], exs[256], cur[256];
    int b = blockIdx.x, t = threadIdx.x;
    int bv = (t < NB) ? bcnt[t] : 0;
    pre[t] = bv;
    __syncthreads();
    for (int o = 1; o < 256; o <<= 1) {
        int u = (t >= o) ? pre[t - o] : 0;
        __syncthreads();
        pre[t] += u;
        __syncthreads();
    }
    int cntb = bcnt[b];
    int base = pre[b] - cntb;          // exclusive prefix
    int cnt = min(cntb, BCAP);
    hist[t] = 0;
    cur[t] = 0;
    __syncthreads();
    for (int j = t; j < cnt; j += 256) {
        unsigned e = bbuf[(size_t)b * BCAP + j];
        se[j] = e;
        atomicAdd(&hist[e >> 17], 1);
    }
    __syncthreads();
    int v = hist[t];
    scn[t] = v;
    __syncthreads();
    for (int o = 1; o < 256; o <<= 1) {
        int u = (t >= o) ? scn[t - o] : 0;
        __syncthreads();
        scn[t] += u;
        __syncthreads();
    }
    int ex = scn[t] - v;
    exs[t] = ex;
    int node = b * 256 + t;
    if (node < NN) row_ptr[node] = base + ex;
    if (b == NB - 1 && t == 0) row_ptr[NN] = NE;
    __syncthreads();
    for (int j = t; j < cnt; j += 256) {
        unsigned e = se[j];
        int dl = e >> 17;
        int p = exs[dl] + atomicAdd(&cur[dl], 1);
        csr_off[base + p] = (int)((e & 0x1FFFFu) << 9);   // src * 512 bytes
    }
}

// ---------------- MFMA GEMM: xlr[N,256](bf16) = Xb[N,128] @ Wcat[128,256] ----------------
__global__ void __launch_bounds__(256) k_gemm_dual_mfma(
    const unsigned short* __restrict__ Xb, const unsigned short* __restrict__ WT,
    unsigned short* __restrict__ C) {
    int w = threadIdx.x >> 6, lane = threadIdx.x & 63;
    int quad = lane >> 4, l16 = lane & 15;
    int r0 = blockIdx.x * 64 + w * 16;
    int lrow = r0 + l16; if (lrow >= NN) lrow = NN - 1;
    const unsigned short* arow = Xb + (size_t)lrow * 128 + quad * 8;
    bf16x8 a[4];
#pragma unroll
    for (int ks = 0; ks < 4; ks++) a[ks] = *(const bf16x8*)(arow + ks * 32);
    f32x4 acc[16];
#pragma unroll
    for (int ct = 0; ct < 16; ct++) acc[ct] = (f32x4){0, 0, 0, 0};
#pragma unroll
    for (int ct = 0; ct < 16; ct++) {
        const unsigned short* bbase = WT + (size_t)(ct * 16 + l16) * 128 + quad * 8;
#pragma unroll
        for (int ks = 0; ks < 4; ks++) {
            bf16x8 b = *(const bf16x8*)(bbase + ks * 32);
            acc[ct] = __builtin_amdgcn_mfma_f32_16x16x32_bf16(a[ks], b, acc[ct], 0, 0, 0);
        }
    }
    int sr = r0 + quad * 4;
#pragma unroll
    for (int ct = 0; ct < 16; ct++) {
#pragma unroll
        for (int r = 0; r < 4; r++) {
            int rr = sr + r;
            if (rr < NN) C[(size_t)rr * 256 + ct * 16 + l16] = f2b(acc[ct][r]);
        }
    }
}

// ---------------- MFMA GEMM skip + inline GraphNorm finalize ----------------
__global__ void __launch_bounds__(256) k_gemm_skip_mfma(
    const unsigned short* __restrict__ hbufb, const float* __restrict__ stats,
    const float* __restrict__ gn_w, const float* __restrict__ gn_b,
    const float* __restrict__ gn_ms, const unsigned short* __restrict__ ST,
    const float* __restrict__ skip_b, unsigned short* __restrict__ Xb16) {
    __shared__ float tot[256];
    __shared__ float scoff_s[256];
    int t = threadIdx.x;
    float s = 0.f;
#pragma unroll
    for (int r = 0; r < REP; r++) s += stats[r * 256 + t];
    tot[t] = s;
    __syncthreads();
    if (t < 128) {
        const float invN = 1.0f / (float)NN;
        float mean = tot[t] * invN;
        float ex2 = tot[128 + t] * invN;
        float ms = gn_ms[t];
        float var = ex2 - (2.f * ms - ms * ms) * mean * mean;
        float wsc = gn_w[t] * rsqrtf(var + EPSN);
        scoff_s[t] = wsc;
        scoff_s[128 + t] = gn_b[t] - wsc * ms * mean;
    }
    __syncthreads();
    int w = t >> 6, lane = t & 63;
    int quad = lane >> 4, l16 = lane & 15;
    int r0 = blockIdx.x * 64 + w * 16;
    int c0 = blockIdx.y * 64;
    int lrow = r0 + l16; if (lrow >= NN) lrow = NN - 1;
    const unsigned short* hrow = hbufb + (size_t)lrow * 128 + quad * 8;
    f32x4 acc0 = {0,0,0,0}, acc1 = {0,0,0,0}, acc2 = {0,0,0,0}, acc3 = {0,0,0,0};
#pragma unroll
    for (int ks = 0; ks < 4; ks++) {
        int k0 = ks * 32;
        int kc = quad * 8 + k0;
        uint4 hw = *(const uint4*)(hrow + k0);
        float2 h01 = up2(hw.x), h23 = up2(hw.y), h45 = up2(hw.z), h67 = up2(hw.w);
        float4 sc0 = *(const float4*)&scoff_s[kc];
        float4 sc1 = *(const float4*)&scoff_s[kc + 4];
        float4 of0 = *(const float4*)&scoff_s[128 + kc];
        float4 of1 = *(const float4*)&scoff_s[128 + kc + 4];
        float e[8];
        e[0] = fmaf(sc0.x, h01.x, of0.x); e[1] = fmaf(sc0.y, h01.y, of0.y);
        e[2] = fmaf(sc0.z, h23.x, of0.z); e[3] = fmaf(sc0.w, h23.y, of0.w);
        e[4] = fmaf(sc1.x, h45.x, of1.x); e[5] = fmaf(sc1.y, h45.y, of1.y);
        e[6] = fmaf(sc1.z, h67.x, of1.z); e[7] = fmaf(sc1.w, h67.y, of1.w);
        bf16x8 a;
#pragma unroll
        for (int j = 0; j < 8; j++) {
            float v = e[j];
            v = (v > 0.f) ? v : (__expf(v) - 1.f);
            a[j] = (short)f2b(v);
        }
        const unsigned short* bbase = ST + (size_t)(c0 + l16) * 128 + quad * 8 + k0;
        bf16x8 b0 = *(const bf16x8*)(bbase);
        bf16x8 b1 = *(const bf16x8*)(bbase + 16 * 128);
        bf16x8 b2 = *(const bf16x8*)(bbase + 32 * 128);
        bf16x8 b3 = *(const bf16x8*)(bbase + 48 * 128);
        acc0 = __builtin_amdgcn_mfma_f32_16x16x32_bf16(a, b0, acc0, 0, 0, 0);
        acc1 = __builtin_amdgcn_mfma_f32_16x16x32_bf16(a, b1, acc1, 0, 0, 0);
        acc2 = __builtin_amdgcn_mfma_f32_16x16x32_bf16(a, b2, acc2, 0, 0, 0);
        acc3 = __builtin_amdgcn_mfma_f32_16x16x32_bf16(a, b3, acc3, 0, 0, 0);
    }
    float sb0 = skip_b[c0 + l16];
    float sb1 = skip_b[c0 + 16 + l16];
    float sb2 = skip_b[c0 + 32 + l16];
    float sb3 = skip_b[c0 + 48 + l16];
    int sr = r0 + quad * 4;
#pragma unroll
    for (int r = 0; r < 4; r++) {
        int rr = sr + r;
        if (rr < NN) {
            size_t base = (size_t)rr * 128 + c0 + l16;
            float v0 = b2f(Xb16[base])      + acc0[r] + sb0;
            float v1 = b2f(Xb16[base + 16]) + acc1[r] + sb1;
            float v2 = b2f(Xb16[base + 32]) + acc2[r] + sb2;
            float v3 = b2f(Xb16[base + 48]) + acc3[r] + sb3;
            Xb16[base]      = f2b(v0);
            Xb16[base + 16] = f2b(v1);
            Xb16[base + 32] = f2b(v2);
            Xb16[base + 48] = f2b(v3);
        }
    }
}

// ---------------- fused GATv2: wave-per-node, shfl-combine, barrier/LDS-free ----------------
// 256-thread blocks = 4 independent waves. Each wave serially handles NPW
// consecutive nodes; within a node its 4 slots (16 lanes each) stride the
// node's edges with depth-2 prefetch (4 independent load chains per wave).
// Cross-slot combine via shfl_xor(16/32): no LDS, no barriers.
// Stats pre-reduced in registers across NPW nodes; atomics from slot 0 only.
// First REP blocks also zero the OTHER layer-parity stats buffer.
__global__ void __launch_bounds__(256) k_gat_node(
    const unsigned short* __restrict__ xlr,
    const float* __restrict__ att, const float* __restrict__ conv_b,
    const int* __restrict__ row_ptr, const int* __restrict__ csr_off,
    unsigned short* __restrict__ houtb, float* __restrict__ stats_cur,
    float* __restrict__ stats_other) {
    int t = threadIdx.x;
    if (blockIdx.x < REP) stats_other[blockIdx.x * 256 + t] = 0.f;
    int wv = t >> 6;
    int lane = t & 63;
    int slot = lane >> 4;        // 0..3
    int l = lane & 15;           // owns channels 8l..8l+7 (head = l>>2)
    const char* xbytes = (const char*)xlr;
    int lofs = 16 * l;
    float2 at2[4];
    float cb[8];
    {
        float4 a0 = *(const float4*)&att[8 * l];
        float4 a1 = *(const float4*)&att[8 * l + 4];
        at2[0] = make_float2(a0.x, a0.y); at2[1] = make_float2(a0.z, a0.w);
        at2[2] = make_float2(a1.x, a1.y); at2[3] = make_float2(a1.z, a1.w);
        float4 c0 = *(const float4*)&conv_b[8 * l];
        float4 c1 = *(const float4*)&conv_b[8 * l + 4];
        cb[0] = c0.x; cb[1] = c0.y; cb[2] = c0.z; cb[3] = c0.w;
        cb[4] = c1.x; cb[5] = c1.y; cb[6] = c1.z; cb[7] = c1.w;
    }
    float ssum[8], ssum2[8];
#pragma unroll
    for (int k = 0; k < 8; k++) { ssum[k] = 0.f; ssum2[k] = 0.f; }
    int gw = blockIdx.x * 4 + wv;
    int n0 = gw * NPW;
    int nEnd = min(n0 + NPW, NN);
    for (int i = n0; i < nEnd; i++) {
        int start = row_ptr[i], end = row_ptr[i + 1];
        uint4 xr_raw = *(const uint4*)(xbytes + (size_t)i * 512 + 256 + lofs);
        float2 xr2[4];
        xr2[0] = up2(xr_raw.x); xr2[1] = up2(xr_raw.y);
        xr2[2] = up2(xr_raw.z); xr2[3] = up2(xr_raw.w);
        float den = 0.f;
        float2 acc[4];
#pragma unroll
        for (int k = 0; k < 4; k++) acc[k] = make_float2(0.f, 0.f);
        // per-slot stream, step 4, depth-2 prefetch (j uniform within slot)
        int j = start + slot;
        bool v0 = j < end;
        int o0 = v0 ? csr_off[j] : 0;
        bool v1 = (j + 4) < end;
        int o1 = v1 ? csr_off[j + 4] : 0;
        uint4 w0 = v0 ? *(const uint4*)(xbytes + (size_t)(unsigned)o0 + lofs)
                      : (uint4){0, 0, 0, 0};
        uint4 w1 = v1 ? *(const uint4*)(xbytes + (size_t)(unsigned)o1 + lofs)
                      : (uint4){0, 0, 0, 0};
        while (v0) {
            bool v2 = (j + 8) < end;
            int o2 = v2 ? csr_off[j + 8] : 0;
            uint4 wp = v2 ? *(const uint4*)(xbytes + (size_t)(unsigned)o2 + lofs)
                          : (uint4){0, 0, 0, 0};
            float2 f0 = up2(w0.x), f1 = up2(w0.y), f2v = up2(w0.z), f3 = up2(w0.w);
            float2 ps = make_float2(0.f, 0.f);
            ps = pk_fma(at2[0], pk_leaky(pk_add(f0, xr2[0])), ps);
            ps = pk_fma(at2[1], pk_leaky(pk_add(f1, xr2[1])), ps);
            ps = pk_fma(at2[2], pk_leaky(pk_add(f2v, xr2[2])), ps);
            ps = pk_fma(at2[3], pk_leaky(pk_add(f3, xr2[3])), ps);
            float p = ps.x + ps.y;
            p += __shfl_xor(p, 1);   // 4-lane head group (within slot)
            p += __shfl_xor(p, 2);
            float w = __expf(p);
            den += w;
            float2 wf = make_float2(w, w);
            acc[0] = pk_fma(wf, f0, acc[0]);
            acc[1] = pk_fma(wf, f1, acc[1]);
            acc[2] = pk_fma(wf, f2v, acc[2]);
            acc[3] = pk_fma(wf, f3, acc[3]);
            j += 4;
            v0 = v1; v1 = v2;
            w0 = w1; w1 = wp;
        }
        // cross-slot combine (lanes l, l+16, l+32, l+48 hold same channels)
#pragma unroll
        for (int k = 0; k < 4; k++) {
            acc[k].x += __shfl_xor(acc[k].x, 16);
            acc[k].y += __shfl_xor(acc[k].y, 16);
            acc[k].x += __shfl_xor(acc[k].x, 32);
            acc[k].y += __shfl_xor(acc[k].y, 32);
        }
        den += __shfl_xor(den, 16);
        den += __shfl_xor(den, 32);
        float inv = 1.f / den;
        float hv0 = fmaf(acc[0].x, inv, cb[0]);
        float hv1 = fmaf(acc[0].y, inv, cb[1]);
        float hv2 = fmaf(acc[1].x, inv, cb[2]);
        float hv3 = fmaf(acc[1].y, inv, cb[3]);
        float hv4 = fmaf(acc[2].x, inv, cb[4]);
        float hv5 = fmaf(acc[2].y, inv, cb[5]);
        float hv6 = fmaf(acc[3].x, inv, cb[6]);
        float hv7 = fmaf(acc[3].y, inv, cb[7]);
        if (slot == 0) {
            uint4 ov;
            ov.x = (unsigned)f2b(hv0) | ((unsigned)f2b(hv1) << 16);
            ov.y = (unsigned)f2b(hv2) | ((unsigned)f2b(hv3) << 16);
            ov.z = (unsigned)f2b(hv4) | ((unsigned)f2b(hv5) << 16);
            ov.w = (unsigned)f2b(hv6) | ((unsigned)f2b(hv7) << 16);
            *(uint4*)&houtb[(size_t)i * HID + 8 * l] = ov;
        }
        ssum[0] += hv0; ssum2[0] += hv0 * hv0;
        ssum[1] += hv1; ssum2[1] += hv1 * hv1;
        ssum[2] += hv2; ssum2[2] += hv2 * hv2;
        ssum[3] += hv3; ssum2[3] += hv3 * hv3;
        ssum[4] += hv4; ssum2[4] += hv4 * hv4;
        ssum[5] += hv5; ssum2[5] += hv5 * hv5;
        ssum[6] += hv6; ssum2[6] += hv6 * hv6;
        ssum[7] += hv7; ssum2[7] += hv7 * hv7;
    }
    if (slot == 0 && n0 < NN) {
        float* srep = stats_cur + (size_t)(gw & (REP - 1)) * 256;
#pragma unroll
        for (int k = 0; k < 8; k++) {
            atomicAdd(&srep[8 * l + k], ssum[k]);
            atomicAdd(&srep[128 + 8 * l + k], ssum2[k]);
        }
    }
}

// ---------------- final fc (bf16 x) ----------------
__global__ void __launch_bounds__(256) k_fc(const unsigned short* __restrict__ xb,
                                            const float* __restrict__ fc_W,
                                            const float* __restrict__ fc_b,
                                            float* __restrict__ out) {
    int t = threadIdx.x;
    int node = blockIdx.x * 4 + (t >> 6);
    int lane = t & 63;
    if (node >= NN) return;
    unsigned xu = *(const unsigned*)&xb[node * HID + lane * 2];
    float2 xv = up2(xu);
    float2 wv = *(const float2*)&fc_W[lane * 2];
    float p = xv.x * wv.x + xv.y * wv.y;
    p += __shfl_xor(p, 32);
    p += __shfl_xor(p, 16);
    p += __shfl_xor(p, 8);
    p += __shfl_xor(p, 4);
    p += __shfl_xor(p, 2);
    p += __shfl_xor(p, 1);
    if (lane == 0) out[node] = p + fc_b[0];
}

extern "C" void kernel_launch(void* const* d_in, const int* in_sizes, int n_in,
                              void* d_out, int out_size, void* d_ws, size_t ws_size,
                              hipStream_t stream) {
    const float* x_in   = (const float*)d_in[0];
    const int*   ei     = (const int*)d_in[1];
    const float* Wl     = (const float*)d_in[2];
    const float* Wr     = (const float*)d_in[3];
    const float* att    = (const float*)d_in[4];
    const float* conv_b = (const float*)d_in[5];
    const float* gn_w   = (const float*)d_in[6];
    const float* gn_b   = (const float*)d_in[7];
    const float* gn_ms  = (const float*)d_in[8];
    const float* skip_W = (const float*)d_in[9];
    const float* skip_b = (const float*)d_in[10];
    const float* fc_W   = (const float*)d_in[11];
    const float* fc_b   = (const float*)d_in[12];
    float* out = (float*)d_out;

    // workspace carve
    float* ws = (float*)d_ws;
    float* stats = ws;                              // 2 * REP * 256 (double-buffered)
    unsigned short* xlr   = (unsigned short*)(stats + 2 * REP * 256);  // N*256 bf16
    unsigned short* b16X  = xlr + (size_t)NN * 256; // N*HID bf16 (residual stream)
    unsigned short* hbufb = b16X + NN * HID;        // N*HID bf16
    unsigned short* wt    = hbufb + NN * HID;       // 4*256*128
    unsigned short* st    = wt + 4 * 256 * 128;     // 128*128
    int* row_ptr = (int*)(st + 128 * 128);          // N+1
    int* bcnt    = row_ptr + NN + 1;                // NB
    int* csr_off = bcnt + NB;                       // NE (byte offsets)
    unsigned* bbuf = (unsigned*)(csr_off + NE);     // NB*BCAP

    k_prep<<<(NN * HID / 4 + 255) / 256, 256, 0, stream>>>(
        x_in, Wl, Wr, skip_W, b16X, wt, st, bcnt, stats);

    // CSR build via bucket sort
    k_bin<<<(NE + TB - 1) / TB, 256, 0, stream>>>(ei, bcnt, bbuf);
    k_bucket_csr<<<NB, 256, 0, stream>>>(bbuf, bcnt, row_ptr, csr_off);

    const int rtiles = (NN + 63) / 64;                    // 782
    const int gat_blocks = (NN + 4 * NPW - 1) / (4 * NPW);  // 1563
    for (int l = 0; l < 4; l++) {
        float* stats_cur   = stats + (size_t)(l & 1) * REP * 256;
        float* stats_other = stats + (size_t)((l + 1) & 1) * REP * 256;
        k_gemm_dual_mfma<<<rtiles, 256, 0, stream>>>(
            b16X, wt + (size_t)l * 256 * 128, xlr);
        k_gat_node<<<gat_blocks, 256, 0, stream>>>(
            xlr, att + l * HID, conv_b + l * HID, row_ptr, csr_off,
            hbufb, stats_cur, stats_other);
        k_gemm_skip_mfma<<<dim3(rtiles, 2), 256, 0, stream>>>(
            hbufb, stats_cur, gn_w + l * HID, gn_b + l * HID, gn_ms + l * HID,
            st, skip_b, b16X);
    }
    k_fc<<<(NN + 3) / 4, 256, 0, stream>>>(b16X, fc_W, fc_b, out);
}

// Round 13
// 624.310 us; speedup vs baseline: 1.9660x; 1.2131x over previous
//
#include <hip/hip_runtime.h>
#include <hip/hip_bf16.h>

#define NN 50000
#define EE 800000
#define NE 850000       // edges + self-loops
#define HID 128
#define NEG_SLOPE 0.2f
#define EPSN 1e-5f
#define NB 196          // buckets of 256 nodes
#define BCAP 6144       // bucket capacity (expected 4352 +- 64)
#define TB 4096         // edges per k_bin block
#define REP 128         // GraphNorm stats replicas (double-buffered)
#define NPB 8           // nodes per k_gat_node block

typedef __attribute__((ext_vector_type(8))) short bf16x8;
typedef __attribute__((ext_vector_type(4))) float f32x4;

__device__ __forceinline__ unsigned short f2b(float f) {
    unsigned u = __float_as_uint(f);
    unsigned r = (u + 0x7FFFu + ((u >> 16) & 1u)) >> 16;
    return (unsigned short)r;
}
__device__ __forceinline__ float b2f(unsigned short u) {
    return __uint_as_float(((unsigned)u) << 16);
}
__device__ __forceinline__ float2 up2(unsigned u) {
    return make_float2(__uint_as_float(u << 16),
                       __uint_as_float(u & 0xFFFF0000u));
}
__device__ __forceinline__ float2 pk_fma(float2 a, float2 b, float2 c) {
    return make_float2(fmaf(a.x, b.x, c.x), fmaf(a.y, b.y, c.y));
}
__device__ __forceinline__ float2 pk_add(float2 a, float2 b) {
    return make_float2(a.x + b.x, a.y + b.y);
}
__device__ __forceinline__ float2 pk_leaky(float2 v) {
    return make_float2(fmaxf(v.x, NEG_SLOPE * v.x), fmaxf(v.y, NEG_SLOPE * v.y));
}

// ---------------- prep: W->bf16^T, x->bf16, zero bcnt + both stats buffers ----------------
__global__ void k_prep(const float* __restrict__ x, const float* __restrict__ Wl,
                       const float* __restrict__ Wr, const float* __restrict__ skip_W,
                       unsigned short* __restrict__ xb, unsigned short* __restrict__ wt,
                       unsigned short* __restrict__ st, int* __restrict__ bcnt,
                       float* __restrict__ stats) {
    int i = blockIdx.x * blockDim.x + threadIdx.x;
    if (i < NN * HID / 4) {
        float4 v = *(const float4*)&x[i * 4];
        ushort4 o = {f2b(v.x), f2b(v.y), f2b(v.z), f2b(v.w)};
        *(ushort4*)&xb[i * 4] = o;
    }
    if (i < NB) bcnt[i] = 0;
    if (i < 2 * REP * 256) stats[i] = 0.f;
    if (i < 4 * 256 * 128) {
        int l = i >> 15, rem = i & 32767;
        int c = rem >> 7, k = rem & 127;
        float v = (c < 128) ? Wl[l * 16384 + k * 128 + c]
                            : Wr[l * 16384 + k * 128 + (c - 128)];
        wt[i] = f2b(v);
    } else if (i < 4 * 256 * 128 + 128 * 128) {
        int j = i - 4 * 256 * 128;
        int c = j >> 7, k = j & 127;
        st[j] = f2b(skip_W[k * 128 + c]);
    }
}

// ---------------- CSR build: bucket sort ----------------
__global__ void __launch_bounds__(256) k_bin(const int* __restrict__ ei,
                                             int* __restrict__ bcnt,
                                             unsigned* __restrict__ bbuf) {
    __shared__ int hist[NB];
    __shared__ int gbase[NB];
    int t = threadIdx.x;
    for (int b = t; b < NB; b += 256) hist[b] = 0;
    __syncthreads();
    int e0 = blockIdx.x * TB;
    unsigned ent[16];
    int bkt[16];
#pragma unroll
    for (int k = 0; k < 16; k++) {
        int e = e0 + k * 256 + t;
        if (e < NE) {
            int src, dst;
            if (e < EE) { src = ei[e]; dst = ei[EE + e]; }
            else        { src = e - EE; dst = src; }
            int b = dst >> 8;
            ent[k] = ((unsigned)(dst & 255) << 17) | (unsigned)src;
            bkt[k] = b;
            atomicAdd(&hist[b], 1);
        } else bkt[k] = -1;
    }
    __syncthreads();
    for (int b = t; b < NB; b += 256) {
        int c = hist[b];
        gbase[b] = (c > 0) ? atomicAdd(&bcnt[b], c) : 0;
        hist[b] = 0;
    }
    __syncthreads();
#pragma unroll
    for (int k = 0; k < 16; k++) {
        int b = bkt[k];
        if (b >= 0) {
            int pos = gbase[b] + atomicAdd(&hist[b], 1);
            if (pos < BCAP) bbuf[(size_t)b * BCAP + pos] = ent[k];
        }
    }
}

// Per-bucket CSR with inline prefix scan of bucket counts; csr stores BYTE
// offsets (src*512) into xlr.
__global__ void __launch_bounds__(256) k_bucket_csr(
    const unsigned* __restrict__ bbuf, const int* __restrict__ bcnt,
    int* __restrict__ row_ptr, int* __restrict__ csr_off) {
    __shared__ unsigned se[BCAP];
    __shared__ int pre[256];
    __shared__ int hist[256], scn[256], exs[256], cur[256];
    int b = blockIdx.x, t = threadIdx.x;
    int bv = (t < NB) ? bcnt[t] : 0;
    pre[t] = bv;
    __syncthreads();
    for (int o = 1; o < 256; o <<= 1) {
        int u = (t >= o) ? pre[t - o] : 0;
        __syncthreads();
        pre[t] += u;
        __syncthreads();
    }
    int cntb = bcnt[b];
    int base = pre[b] - cntb;          // exclusive prefix
    int cnt = min(cntb, BCAP);
    hist[t] = 0;
    cur[t] = 0;
    __syncthreads();
    for (int j = t; j < cnt; j += 256) {
        unsigned e = bbuf[(size_t)b * BCAP + j];
        se[j] = e;
        atomicAdd(&hist[e >> 17], 1);
    }
    __syncthreads();
    int v = hist[t];
    scn[t] = v;
    __syncthreads();
    for (int o = 1; o < 256; o <<= 1) {
        int u = (t >= o) ? scn[t - o] : 0;
        __syncthreads();
        scn[t] += u;
        __syncthreads();
    }
    int ex = scn[t] - v;
    exs[t] = ex;
    int node = b * 256 + t;
    if (node < NN) row_ptr[node] = base + ex;
    if (b == NB - 1 && t == 0) row_ptr[NN] = NE;
    __syncthreads();
    for (int j = t; j < cnt; j += 256) {
        unsigned e = se[j];
        int dl = e >> 17;
        int p = exs[dl] + atomicAdd(&cur[dl], 1);
        csr_off[base + p] = (int)((e & 0x1FFFFu) << 9);   // src * 512 bytes
    }
}

// ---------------- MFMA GEMM: xlr[N,256](bf16) = Xb[N,128] @ Wcat[128,256] ----------------
__global__ void __launch_bounds__(256) k_gemm_dual_mfma(
    const unsigned short* __restrict__ Xb, const unsigned short* __restrict__ WT,
    unsigned short* __restrict__ C) {
    int w = threadIdx.x >> 6, lane = threadIdx.x & 63;
    int quad = lane >> 4, l16 = lane & 15;
    int r0 = blockIdx.x * 64 + w * 16;
    int lrow = r0 + l16; if (lrow >= NN) lrow = NN - 1;
    const unsigned short* arow = Xb + (size_t)lrow * 128 + quad * 8;
    bf16x8 a[4];
#pragma unroll
    for (int ks = 0; ks < 4; ks++) a[ks] = *(const bf16x8*)(arow + ks * 32);
    f32x4 acc[16];
#pragma unroll
    for (int ct = 0; ct < 16; ct++) acc[ct] = (f32x4){0, 0, 0, 0};
#pragma unroll
    for (int ct = 0; ct < 16; ct++) {
        const unsigned short* bbase = WT + (size_t)(ct * 16 + l16) * 128 + quad * 8;
#pragma unroll
        for (int ks = 0; ks < 4; ks++) {
            bf16x8 b = *(const bf16x8*)(bbase + ks * 32);
            acc[ct] = __builtin_amdgcn_mfma_f32_16x16x32_bf16(a[ks], b, acc[ct], 0, 0, 0);
        }
    }
    int sr = r0 + quad * 4;
#pragma unroll
    for (int ct = 0; ct < 16; ct++) {
#pragma unroll
        for (int r = 0; r < 4; r++) {
            int rr = sr + r;
            if (rr < NN) C[(size_t)rr * 256 + ct * 16 + l16] = f2b(acc[ct][r]);
        }
    }
}

// ---------------- MFMA GEMM skip + inline GraphNorm finalize ----------------
__global__ void __launch_bounds__(256) k_gemm_skip_mfma(
    const unsigned short* __restrict__ hbufb, const float* __restrict__ stats,
    const float* __restrict__ gn_w, const float* __restrict__ gn_b,
    const float* __restrict__ gn_ms, const unsigned short* __restrict__ ST,
    const float* __restrict__ skip_b, unsigned short* __restrict__ Xb16) {
    __shared__ float tot[256];
    __shared__ float scoff_s[256];
    int t = threadIdx.x;
    float s = 0.f;
#pragma unroll 8
    for (int r = 0; r < REP; r++) s += stats[r * 256 + t];
    tot[t] = s;
    __syncthreads();
    if (t < 128) {
        const float invN = 1.0f / (float)NN;
        float mean = tot[t] * invN;
        float ex2 = tot[128 + t] * invN;
        float ms = gn_ms[t];
        float var = ex2 - (2.f * ms - ms * ms) * mean * mean;
        float wsc = gn_w[t] * rsqrtf(var + EPSN);
        scoff_s[t] = wsc;
        scoff_s[128 + t] = gn_b[t] - wsc * ms * mean;
    }
    __syncthreads();
    int w = t >> 6, lane = t & 63;
    int quad = lane >> 4, l16 = lane & 15;
    int r0 = blockIdx.x * 64 + w * 16;
    int c0 = blockIdx.y * 64;
    int lrow = r0 + l16; if (lrow >= NN) lrow = NN - 1;
    const unsigned short* hrow = hbufb + (size_t)lrow * 128 + quad * 8;
    f32x4 acc0 = {0,0,0,0}, acc1 = {0,0,0,0}, acc2 = {0,0,0,0}, acc3 = {0,0,0,0};
#pragma unroll
    for (int ks = 0; ks < 4; ks++) {
        int k0 = ks * 32;
        int kc = quad * 8 + k0;
        uint4 hw = *(const uint4*)(hrow + k0);
        float2 h01 = up2(hw.x), h23 = up2(hw.y), h45 = up2(hw.z), h67 = up2(hw.w);
        float4 sc0 = *(const float4*)&scoff_s[kc];
        float4 sc1 = *(const float4*)&scoff_s[kc + 4];
        float4 of0 = *(const float4*)&scoff_s[128 + kc];
        float4 of1 = *(const float4*)&scoff_s[128 + kc + 4];
        float e[8];
        e[0] = fmaf(sc0.x, h01.x, of0.x); e[1] = fmaf(sc0.y, h01.y, of0.y);
        e[2] = fmaf(sc0.z, h23.x, of0.z); e[3] = fmaf(sc0.w, h23.y, of0.w);
        e[4] = fmaf(sc1.x, h45.x, of1.x); e[5] = fmaf(sc1.y, h45.y, of1.y);
        e[6] = fmaf(sc1.z, h67.x, of1.z); e[7] = fmaf(sc1.w, h67.y, of1.w);
        bf16x8 a;
#pragma unroll
        for (int j = 0; j < 8; j++) {
            float v = e[j];
            v = (v > 0.f) ? v : (__expf(v) - 1.f);
            a[j] = (short)f2b(v);
        }
        const unsigned short* bbase = ST + (size_t)(c0 + l16) * 128 + quad * 8 + k0;
        bf16x8 b0 = *(const bf16x8*)(bbase);
        bf16x8 b1 = *(const bf16x8*)(bbase + 16 * 128);
        bf16x8 b2 = *(const bf16x8*)(bbase + 32 * 128);
        bf16x8 b3 = *(const bf16x8*)(bbase + 48 * 128);
        acc0 = __builtin_amdgcn_mfma_f32_16x16x32_bf16(a, b0, acc0, 0, 0, 0);
        acc1 = __builtin_amdgcn_mfma_f32_16x16x32_bf16(a, b1, acc1, 0, 0, 0);
        acc2 = __builtin_amdgcn_mfma_f32_16x16x32_bf16(a, b2, acc2, 0, 0, 0);
        acc3 = __builtin_amdgcn_mfma_f32_16x16x32_bf16(a, b3, acc3, 0, 0, 0);
    }
    float sb0 = skip_b[c0 + l16];
    float sb1 = skip_b[c0 + 16 + l16];
    float sb2 = skip_b[c0 + 32 + l16];
    float sb3 = skip_b[c0 + 48 + l16];
    int sr = r0 + quad * 4;
#pragma unroll
    for (int r = 0; r < 4; r++) {
        int rr = sr + r;
        if (rr < NN) {
            size_t base = (size_t)rr * 128 + c0 + l16;
            float v0 = b2f(Xb16[base])      + acc0[r] + sb0;
            float v1 = b2f(Xb16[base + 16]) + acc1[r] + sb1;
            float v2 = b2f(Xb16[base + 32]) + acc2[r] + sb2;
            float v3 = b2f(Xb16[base + 48]) + acc3[r] + sb3;
            Xb16[base]      = f2b(v0);
            Xb16[base + 16] = f2b(v1);
            Xb16[base + 32] = f2b(v2);
            Xb16[base + 48] = f2b(v3);
        }
    }
}

// ---------------- fused GATv2 (R10 structure): 8 slots stride one node ----------------
// 128-thr block, 8 slots x 16 lanes; NPB serial nodes/block; direct byte-offset
// loads, depth-2 pipeline, parity-buffered LDS epilogue (1 barrier/node).
// Stats pre-reduced in registers across NPB nodes -> 2 atomics/thread into
// REP=128 replicas. First REP blocks zero the OTHER layer-parity buffer.
__global__ void __launch_bounds__(128) k_gat_node(
    const unsigned short* __restrict__ xlr,
    const float* __restrict__ att, const float* __restrict__ conv_b,
    const int* __restrict__ row_ptr, const int* __restrict__ csr_off,
    unsigned short* __restrict__ houtb, float* __restrict__ stats_cur,
    float* __restrict__ stats_other) {
    int t = threadIdx.x;
    int g = t >> 4;          // slot 0..7
    int l = t & 15;          // lane in slot: owns channels 8l..8l+7
    if (blockIdx.x < REP) {
        stats_other[blockIdx.x * 256 + t] = 0.f;
        stats_other[blockIdx.x * 256 + 128 + t] = 0.f;
    }
    const char* xbytes = (const char*)xlr;
    int lofs = 16 * l;
    float2 at2[4];
    {
        float4 a0 = *(const float4*)&att[8 * l];
        float4 a1 = *(const float4*)&att[8 * l + 4];
        at2[0] = make_float2(a0.x, a0.y); at2[1] = make_float2(a0.z, a0.w);
        at2[2] = make_float2(a1.x, a1.y); at2[3] = make_float2(a1.z, a1.w);
    }
    float cb = conv_b[t];
    int i0 = blockIdx.x * NPB;
    int rp[NPB + 1];
#pragma unroll
    for (int k = 0; k <= NPB; k++) rp[k] = row_ptr[i0 + k];   // wave-uniform -> scalar
    __shared__ float s_acc[2][8][16][12];
    __shared__ float s_den[2][8][16];
    float ssum = 0.f, ssum2 = 0.f;
    uint4 xr_next = *(const uint4*)(xbytes + (size_t)i0 * 512 + 256 + lofs);
    for (int nn = 0; nn < NPB; nn++) {
        int i = i0 + nn;
        uint4 xr_raw = xr_next;
        if (nn + 1 < NPB)
            xr_next = *(const uint4*)(xbytes + (size_t)(i + 1) * 512 + 256 + lofs);
        float2 xr2[4];
        xr2[0] = up2(xr_raw.x); xr2[1] = up2(xr_raw.y);
        xr2[2] = up2(xr_raw.z); xr2[3] = up2(xr_raw.w);
        int start = rp[nn], end = rp[nn + 1];
        float den = 0.f;
        float2 acc[4];
#pragma unroll
        for (int k = 0; k < 4; k++) acc[k] = make_float2(0.f, 0.f);
        // depth-2 pipeline: rows for j and j+8 in flight, offset for j+16
        int j = start + g;
        bool v0 = j < end;
        int o0 = v0 ? csr_off[j] : 0;
        bool v1 = (j + 8) < end;
        int o1 = v1 ? csr_off[j + 8] : 0;
        uint4 xw0 = {0,0,0,0}, xw1 = {0,0,0,0};
        if (v0) xw0 = *(const uint4*)(xbytes + (size_t)(unsigned)o0 + lofs);
        if (v1) xw1 = *(const uint4*)(xbytes + (size_t)(unsigned)o1 + lofs);
        while (v0) {
            bool v2 = (j + 16) < end;
            int o2 = v2 ? csr_off[j + 16] : 0;
            uint4 xw2 = {0,0,0,0};
            if (v2) xw2 = *(const uint4*)(xbytes + (size_t)(unsigned)o2 + lofs);
            float2 f0 = up2(xw0.x), f1 = up2(xw0.y), f2v = up2(xw0.z), f3 = up2(xw0.w);
            float2 ps = make_float2(0.f, 0.f);
            ps = pk_fma(at2[0], pk_leaky(pk_add(f0, xr2[0])), ps);
            ps = pk_fma(at2[1], pk_leaky(pk_add(f1, xr2[1])), ps);
            ps = pk_fma(at2[2], pk_leaky(pk_add(f2v, xr2[2])), ps);
            ps = pk_fma(at2[3], pk_leaky(pk_add(f3, xr2[3])), ps);
            float p = ps.x + ps.y;
            p += __shfl_xor(p, 1);   // 4-lane head group
            p += __shfl_xor(p, 2);
            float w = __expf(p);
            den += w;
            float2 w2 = make_float2(w, w);
            acc[0] = pk_fma(w2, f0, acc[0]);
            acc[1] = pk_fma(w2, f1, acc[1]);
            acc[2] = pk_fma(w2, f2v, acc[2]);
            acc[3] = pk_fma(w2, f3, acc[3]);
            j += 8;
            v0 = v1; v1 = v2;
            xw0 = xw1; xw1 = xw2;
        }
        int par = nn & 1;
        *(float4*)&s_acc[par][g][l][0] = make_float4(acc[0].x, acc[0].y, acc[1].x, acc[1].y);
        *(float4*)&s_acc[par][g][l][4] = make_float4(acc[2].x, acc[2].y, acc[3].x, acc[3].y);
        s_den[par][g][l] = den;
        __syncthreads();
        int cl = t >> 3, cj = t & 7;
        float a = 0.f, d = 0.f;
#pragma unroll
        for (int gg = 0; gg < 8; gg++) {
            a += s_acc[par][gg][cl][cj];
            d += s_den[par][gg][cl];
        }
        float hv = a / d + cb;
        houtb[(size_t)i * HID + t] = f2b(hv);
        ssum += hv;
        ssum2 += hv * hv;
        // no trailing barrier: next node uses the other parity buffer
    }
    float* srep = stats_cur + (size_t)(blockIdx.x & (REP - 1)) * 256;
    atomicAdd(&srep[t], ssum);
    atomicAdd(&srep[128 + t], ssum2);
}

// ---------------- final fc (bf16 x) ----------------
__global__ void __launch_bounds__(256) k_fc(const unsigned short* __restrict__ xb,
                                            const float* __restrict__ fc_W,
                                            const float* __restrict__ fc_b,
                                            float* __restrict__ out) {
    int t = threadIdx.x;
    int node = blockIdx.x * 4 + (t >> 6);
    int lane = t & 63;
    if (node >= NN) return;
    unsigned xu = *(const unsigned*)&xb[node * HID + lane * 2];
    float2 xv = up2(xu);
    float2 wv = *(const float2*)&fc_W[lane * 2];
    float p = xv.x * wv.x + xv.y * wv.y;
    p += __shfl_xor(p, 32);
    p += __shfl_xor(p, 16);
    p += __shfl_xor(p, 8);
    p += __shfl_xor(p, 4);
    p += __shfl_xor(p, 2);
    p += __shfl_xor(p, 1);
    if (lane == 0) out[node] = p + fc_b[0];
}

extern "C" void kernel_launch(void* const* d_in, const int* in_sizes, int n_in,
                              void* d_out, int out_size, void* d_ws, size_t ws_size,
                              hipStream_t stream) {
    const float* x_in   = (const float*)d_in[0];
    const int*   ei     = (const int*)d_in[1];
    const float* Wl     = (const float*)d_in[2];
    const float* Wr     = (const float*)d_in[3];
    const float* att    = (const float*)d_in[4];
    const float* conv_b = (const float*)d_in[5];
    const float* gn_w   = (const float*)d_in[6];
    const float* gn_b   = (const float*)d_in[7];
    const float* gn_ms  = (const float*)d_in[8];
    const float* skip_W = (const float*)d_in[9];
    const float* skip_b = (const float*)d_in[10];
    const float* fc_W   = (const float*)d_in[11];
    const float* fc_b   = (const float*)d_in[12];
    float* out = (float*)d_out;

    // workspace carve
    float* ws = (float*)d_ws;
    float* stats = ws;                              // 2 * REP * 256 (double-buffered)
    unsigned short* xlr   = (unsigned short*)(stats + 2 * REP * 256);  // N*256 bf16
    unsigned short* b16X  = xlr + (size_t)NN * 256; // N*HID bf16 (residual stream)
    unsigned short* hbufb = b16X + NN * HID;        // N*HID bf16
    unsigned short* wt    = hbufb + NN * HID;       // 4*256*128
    unsigned short* st    = wt + 4 * 256 * 128;     // 128*128
    int* row_ptr = (int*)(st + 128 * 128);          // N+1
    int* bcnt    = row_ptr + NN + 1;                // NB
    int* csr_off = bcnt + NB;                       // NE (byte offsets)
    unsigned* bbuf = (unsigned*)(csr_off + NE);     // NB*BCAP

    k_prep<<<(NN * HID / 4 + 255) / 256, 256, 0, stream>>>(
        x_in, Wl, Wr, skip_W, b16X, wt, st, bcnt, stats);

    // CSR build via bucket sort
    k_bin<<<(NE + TB - 1) / TB, 256, 0, stream>>>(ei, bcnt, bbuf);
    k_bucket_csr<<<NB, 256, 0, stream>>>(bbuf, bcnt, row_ptr, csr_off);

    const int rtiles = (NN + 63) / 64;              // 782
    const int gat_blocks = (NN + NPB - 1) / NPB;    // 6250
    for (int l = 0; l < 4; l++) {
        float* stats_cur   = stats + (size_t)(l & 1) * REP * 256;
        float* stats_other = stats + (size_t)((l + 1) & 1) * REP * 256;
        k_gemm_dual_mfma<<<rtiles, 256, 0, stream>>>(
            b16X, wt + (size_t)l * 256 * 128, xlr);
        k_gat_node<<<gat_blocks, 128, 0, stream>>>(
            xlr, att + l * HID, conv_b + l * HID, row_ptr, csr_off,
            hbufb, stats_cur, stats_other);
        k_gemm_skip_mfma<<<dim3(rtiles, 2), 256, 0, stream>>>(
            hbufb, stats_cur, gn_w + l * HID, gn_b + l * HID, gn_ms + l * HID,
            st, skip_b, b16X);
    }
    k_fc<<<(NN + 3) / 4, 256, 0, stream>>>(b16X, fc_W, fc_b, out);
}

// Round 14
// 613.578 us; speedup vs baseline: 2.0004x; 1.0175x over previous
//
#include <hip/hip_runtime.h>
#include <hip/hip_bf16.h>

#define NN 50000
#define EE 800000
#define NE 850000       // edges + self-loops
#define HID 128
#define NEG_SLOPE 0.2f
#define EPSN 1e-5f
#define NB 196          // buckets of 256 nodes
#define BCAP 6144       // bucket capacity (expected 4352 +- 64)
#define TB 4096         // edges per k_bin block
#define REP 128         // GraphNorm stats replicas
#define NPB 8           // nodes per k_gat_node block

typedef __attribute__((ext_vector_type(8))) short bf16x8;
typedef __attribute__((ext_vector_type(4))) float f32x4;

__device__ __forceinline__ unsigned short f2b(float f) {
    unsigned u = __float_as_uint(f);
    unsigned r = (u + 0x7FFFu + ((u >> 16) & 1u)) >> 16;
    return (unsigned short)r;
}
__device__ __forceinline__ float b2f(unsigned short u) {
    return __uint_as_float(((unsigned)u) << 16);
}
__device__ __forceinline__ float2 up2(unsigned u) {
    return make_float2(__uint_as_float(u << 16),
                       __uint_as_float(u & 0xFFFF0000u));
}
__device__ __forceinline__ float2 pk_fma(float2 a, float2 b, float2 c) {
    return make_float2(fmaf(a.x, b.x, c.x), fmaf(a.y, b.y, c.y));
}
__device__ __forceinline__ float2 pk_add(float2 a, float2 b) {
    return make_float2(a.x + b.x, a.y + b.y);
}
__device__ __forceinline__ float2 pk_leaky(float2 v) {
    return make_float2(fmaxf(v.x, NEG_SLOPE * v.x), fmaxf(v.y, NEG_SLOPE * v.y));
}

// ---------------- prep: W->bf16^T, x->bf16, zero bcnt + stats ----------------
__global__ void k_prep(const float* __restrict__ x, const float* __restrict__ Wl,
                       const float* __restrict__ Wr, const float* __restrict__ skip_W,
                       unsigned short* __restrict__ xb, unsigned short* __restrict__ wt,
                       unsigned short* __restrict__ st, int* __restrict__ bcnt,
                       float* __restrict__ stats) {
    int i = blockIdx.x * blockDim.x + threadIdx.x;
    if (i < NN * HID / 4) {
        float4 v = *(const float4*)&x[i * 4];
        ushort4 o = {f2b(v.x), f2b(v.y), f2b(v.z), f2b(v.w)};
        *(ushort4*)&xb[i * 4] = o;
    }
    if (i < NB) bcnt[i] = 0;
    if (i < REP * 256) stats[i] = 0.f;
    if (i < 4 * 256 * 128) {
        int l = i >> 15, rem = i & 32767;
        int c = rem >> 7, k = rem & 127;
        float v = (c < 128) ? Wl[l * 16384 + k * 128 + c]
                            : Wr[l * 16384 + k * 128 + (c - 128)];
        wt[i] = f2b(v);
    } else if (i < 4 * 256 * 128 + 128 * 128) {
        int j = i - 4 * 256 * 128;
        int c = j >> 7, k = j & 127;
        st[j] = f2b(skip_W[k * 128 + c]);
    }
}

// ---------------- CSR build: bucket sort ----------------
__global__ void __launch_bounds__(256) k_bin(const int* __restrict__ ei,
                                             int* __restrict__ bcnt,
                                             unsigned* __restrict__ bbuf) {
    __shared__ int hist[NB];
    __shared__ int gbase[NB];
    int t = threadIdx.x;
    for (int b = t; b < NB; b += 256) hist[b] = 0;
    __syncthreads();
    int e0 = blockIdx.x * TB;
    unsigned ent[16];
    int bkt[16];
#pragma unroll
    for (int k = 0; k < 16; k++) {
        int e = e0 + k * 256 + t;
        if (e < NE) {
            int src, dst;
            if (e < EE) { src = ei[e]; dst = ei[EE + e]; }
            else        { src = e - EE; dst = src; }
            int b = dst >> 8;
            ent[k] = ((unsigned)(dst & 255) << 17) | (unsigned)src;
            bkt[k] = b;
            atomicAdd(&hist[b], 1);
        } else bkt[k] = -1;
    }
    __syncthreads();
    for (int b = t; b < NB; b += 256) {
        int c = hist[b];
        gbase[b] = (c > 0) ? atomicAdd(&bcnt[b], c) : 0;
        hist[b] = 0;
    }
    __syncthreads();
#pragma unroll
    for (int k = 0; k < 16; k++) {
        int b = bkt[k];
        if (b >= 0) {
            int pos = gbase[b] + atomicAdd(&hist[b], 1);
            if (pos < BCAP) bbuf[(size_t)b * BCAP + pos] = ent[k];
        }
    }
}

// Per-bucket CSR with inline prefix scan of bucket counts; csr stores BYTE
// offsets (src*512) into xlr.
__global__ void __launch_bounds__(256) k_bucket_csr(
    const unsigned* __restrict__ bbuf, const int* __restrict__ bcnt,
    int* __restrict__ row_ptr, int* __restrict__ csr_off) {
    __shared__ unsigned se[BCAP];
    __shared__ int pre[256];
    __shared__ int hist[256], scn[256], exs[256], cur[256];
    int b = blockIdx.x, t = threadIdx.x;
    int bv = (t < NB) ? bcnt[t] : 0;
    pre[t] = bv;
    __syncthreads();
    for (int o = 1; o < 256; o <<= 1) {
        int u = (t >= o) ? pre[t - o] : 0;
        __syncthreads();
        pre[t] += u;
        __syncthreads();
    }
    int cntb = bcnt[b];
    int base = pre[b] - cntb;          // exclusive prefix
    int cnt = min(cntb, BCAP);
    hist[t] = 0;
    cur[t] = 0;
    __syncthreads();
    for (int j = t; j < cnt; j += 256) {
        unsigned e = bbuf[(size_t)b * BCAP + j];
        se[j] = e;
        atomicAdd(&hist[e >> 17], 1);
    }
    __syncthreads();
    int v = hist[t];
    scn[t] = v;
    __syncthreads();
    for (int o = 1; o < 256; o <<= 1) {
        int u = (t >= o) ? scn[t - o] : 0;
        __syncthreads();
        scn[t] += u;
        __syncthreads();
    }
    int ex = scn[t] - v;
    exs[t] = ex;
    int node = b * 256 + t;
    if (node < NN) row_ptr[node] = base + ex;
    if (b == NB - 1 && t == 0) row_ptr[NN] = NE;
    __syncthreads();
    for (int j = t; j < cnt; j += 256) {
        unsigned e = se[j];
        int dl = e >> 17;
        int p = exs[dl] + atomicAdd(&cur[dl], 1);
        csr_off[base + p] = (int)((e & 0x1FFFFu) << 9);   // src * 512 bytes
    }
}

// ---------------- MFMA GEMM: xlr[N,256](bf16) = Xb[N,128] @ Wcat[128,256] ----------------
__global__ void __launch_bounds__(256) k_gemm_dual_mfma(
    const unsigned short* __restrict__ Xb, const unsigned short* __restrict__ WT,
    unsigned short* __restrict__ C) {
    int w = threadIdx.x >> 6, lane = threadIdx.x & 63;
    int quad = lane >> 4, l16 = lane & 15;
    int r0 = blockIdx.x * 64 + w * 16;
    int lrow = r0 + l16; if (lrow >= NN) lrow = NN - 1;
    const unsigned short* arow = Xb + (size_t)lrow * 128 + quad * 8;
    bf16x8 a[4];
#pragma unroll
    for (int ks = 0; ks < 4; ks++) a[ks] = *(const bf16x8*)(arow + ks * 32);
    f32x4 acc[16];
#pragma unroll
    for (int ct = 0; ct < 16; ct++) acc[ct] = (f32x4){0, 0, 0, 0};
#pragma unroll
    for (int ct = 0; ct < 16; ct++) {
        const unsigned short* bbase = WT + (size_t)(ct * 16 + l16) * 128 + quad * 8;
#pragma unroll
        for (int ks = 0; ks < 4; ks++) {
            bf16x8 b = *(const bf16x8*)(bbase + ks * 32);
            acc[ct] = __builtin_amdgcn_mfma_f32_16x16x32_bf16(a[ks], b, acc[ct], 0, 0, 0);
        }
    }
    int sr = r0 + quad * 4;
#pragma unroll
    for (int ct = 0; ct < 16; ct++) {
#pragma unroll
        for (int r = 0; r < 4; r++) {
            int rr = sr + r;
            if (rr < NN) C[(size_t)rr * 256 + ct * 16 + l16] = f2b(acc[ct][r]);
        }
    }
}

// ---------------- reduce stats replicas -> scale/offset; re-zero replicas ----------------
__global__ void __launch_bounds__(1024) k_finalize(
    float* __restrict__ stats, const float* __restrict__ gn_w,
    const float* __restrict__ gn_b, const float* __restrict__ gn_ms,
    float* __restrict__ scoff) {
    __shared__ float red[1024];
    __shared__ float tot[256];
    int t = threadIdx.x;
    int col = t & 255, part = t >> 8;          // 4 parts x 32 replicas
    float s = 0.f;
    for (int r = part * (REP / 4); r < (part + 1) * (REP / 4); r++)
        s += stats[(size_t)r * 256 + col];
    red[t] = s;
    __syncthreads();
    if (part == 0) tot[col] = red[col] + red[col + 256] + red[col + 512] + red[col + 768];
    __syncthreads();
    for (int j = t; j < REP * 256; j += 1024) stats[j] = 0.f;   // re-zero for next layer
    if (t < 128) {
        const float invN = 1.0f / (float)NN;
        float mean = tot[t] * invN;
        float ex2 = tot[128 + t] * invN;
        float ms = gn_ms[t];
        float var = ex2 - (2.f * ms - ms * ms) * mean * mean;
        float wsc = gn_w[t] * rsqrtf(var + EPSN);
        scoff[t] = wsc;
        scoff[128 + t] = gn_b[t] - wsc * ms * mean;
    }
}

// ---------------- MFMA GEMM skip: Xb16 += ELU(scale*h+off)@skipW + b (bf16) ----------------
__global__ void __launch_bounds__(256) k_gemm_skip_mfma(
    const unsigned short* __restrict__ hbufb, const float* __restrict__ scoff,
    const unsigned short* __restrict__ ST,
    const float* __restrict__ skip_b, unsigned short* __restrict__ Xb16) {
    int t = threadIdx.x;
    int w = t >> 6, lane = t & 63;
    int quad = lane >> 4, l16 = lane & 15;
    int r0 = blockIdx.x * 64 + w * 16;
    int c0 = blockIdx.y * 64;
    int lrow = r0 + l16; if (lrow >= NN) lrow = NN - 1;
    const unsigned short* hrow = hbufb + (size_t)lrow * 128 + quad * 8;
    f32x4 acc0 = {0,0,0,0}, acc1 = {0,0,0,0}, acc2 = {0,0,0,0}, acc3 = {0,0,0,0};
#pragma unroll
    for (int ks = 0; ks < 4; ks++) {
        int k0 = ks * 32;
        int kc = quad * 8 + k0;
        uint4 hw = *(const uint4*)(hrow + k0);
        float2 h01 = up2(hw.x), h23 = up2(hw.y), h45 = up2(hw.z), h67 = up2(hw.w);
        float4 sc0 = *(const float4*)(scoff + kc);
        float4 sc1 = *(const float4*)(scoff + kc + 4);
        float4 of0 = *(const float4*)(scoff + 128 + kc);
        float4 of1 = *(const float4*)(scoff + 128 + kc + 4);
        float e[8];
        e[0] = fmaf(sc0.x, h01.x, of0.x); e[1] = fmaf(sc0.y, h01.y, of0.y);
        e[2] = fmaf(sc0.z, h23.x, of0.z); e[3] = fmaf(sc0.w, h23.y, of0.w);
        e[4] = fmaf(sc1.x, h45.x, of1.x); e[5] = fmaf(sc1.y, h45.y, of1.y);
        e[6] = fmaf(sc1.z, h67.x, of1.z); e[7] = fmaf(sc1.w, h67.y, of1.w);
        bf16x8 a;
#pragma unroll
        for (int j = 0; j < 8; j++) {
            float v = e[j];
            v = (v > 0.f) ? v : (__expf(v) - 1.f);
            a[j] = (short)f2b(v);
        }
        const unsigned short* bbase = ST + (size_t)(c0 + l16) * 128 + quad * 8 + k0;
        bf16x8 b0 = *(const bf16x8*)(bbase);
        bf16x8 b1 = *(const bf16x8*)(bbase + 16 * 128);
        bf16x8 b2 = *(const bf16x8*)(bbase + 32 * 128);
        bf16x8 b3 = *(const bf16x8*)(bbase + 48 * 128);
        acc0 = __builtin_amdgcn_mfma_f32_16x16x32_bf16(a, b0, acc0, 0, 0, 0);
        acc1 = __builtin_amdgcn_mfma_f32_16x16x32_bf16(a, b1, acc1, 0, 0, 0);
        acc2 = __builtin_amdgcn_mfma_f32_16x16x32_bf16(a, b2, acc2, 0, 0, 0);
        acc3 = __builtin_amdgcn_mfma_f32_16x16x32_bf16(a, b3, acc3, 0, 0, 0);
    }
    float sb0 = skip_b[c0 + l16];
    float sb1 = skip_b[c0 + 16 + l16];
    float sb2 = skip_b[c0 + 32 + l16];
    float sb3 = skip_b[c0 + 48 + l16];
    int sr = r0 + quad * 4;
#pragma unroll
    for (int r = 0; r < 4; r++) {
        int rr = sr + r;
        if (rr < NN) {
            size_t base = (size_t)rr * 128 + c0 + l16;
            float v0 = b2f(Xb16[base])      + acc0[r] + sb0;
            float v1 = b2f(Xb16[base + 16]) + acc1[r] + sb1;
            float v2 = b2f(Xb16[base + 32]) + acc2[r] + sb2;
            float v3 = b2f(Xb16[base + 48]) + acc3[r] + sb3;
            Xb16[base]      = f2b(v0);
            Xb16[base + 16] = f2b(v1);
            Xb16[base + 32] = f2b(v2);
            Xb16[base + 48] = f2b(v3);
        }
    }
}

// ---------------- fused GATv2 (R10 structure): 8 slots stride one node ----------------
__global__ void __launch_bounds__(128) k_gat_node(
    const unsigned short* __restrict__ xlr,
    const float* __restrict__ att, const float* __restrict__ conv_b,
    const int* __restrict__ row_ptr, const int* __restrict__ csr_off,
    unsigned short* __restrict__ houtb, float* __restrict__ stats) {
    int t = threadIdx.x;
    int g = t >> 4;          // slot 0..7
    int l = t & 15;          // lane in slot: owns channels 8l..8l+7
    const char* xbytes = (const char*)xlr;
    int lofs = 16 * l;
    float2 at2[4];
    {
        float4 a0 = *(const float4*)&att[8 * l];
        float4 a1 = *(const float4*)&att[8 * l + 4];
        at2[0] = make_float2(a0.x, a0.y); at2[1] = make_float2(a0.z, a0.w);
        at2[2] = make_float2(a1.x, a1.y); at2[3] = make_float2(a1.z, a1.w);
    }
    float cb = conv_b[t];
    int i0 = blockIdx.x * NPB;
    int rp[NPB + 1];
#pragma unroll
    for (int k = 0; k <= NPB; k++) rp[k] = row_ptr[i0 + k];   // wave-uniform -> scalar
    __shared__ float s_acc[2][8][16][12];
    __shared__ float s_den[2][8][16];
    float ssum = 0.f, ssum2 = 0.f;
    uint4 xr_next = *(const uint4*)(xbytes + (size_t)i0 * 512 + 256 + lofs);
    for (int nn = 0; nn < NPB; nn++) {
        int i = i0 + nn;
        uint4 xr_raw = xr_next;
        if (nn + 1 < NPB)
            xr_next = *(const uint4*)(xbytes + (size_t)(i + 1) * 512 + 256 + lofs);
        float2 xr2[4];
        xr2[0] = up2(xr_raw.x); xr2[1] = up2(xr_raw.y);
        xr2[2] = up2(xr_raw.z); xr2[3] = up2(xr_raw.w);
        int start = rp[nn], end = rp[nn + 1];
        float den = 0.f;
        float2 acc[4];
#pragma unroll
        for (int k = 0; k < 4; k++) acc[k] = make_float2(0.f, 0.f);
        int j = start + g;
        bool v0 = j < end;
        int o0 = v0 ? csr_off[j] : 0;
        bool v1 = (j + 8) < end;
        int o1 = v1 ? csr_off[j + 8] : 0;
        uint4 xw0 = {0,0,0,0}, xw1 = {0,0,0,0};
        if (v0) xw0 = *(const uint4*)(xbytes + (size_t)(unsigned)o0 + lofs);
        if (v1) xw1 = *(const uint4*)(xbytes + (size_t)(unsigned)o1 + lofs);
        while (v0) {
            bool v2 = (j + 16) < end;
            int o2 = v2 ? csr_off[j + 16] : 0;
            uint4 xw2 = {0,0,0,0};
            if (v2) xw2 = *(const uint4*)(xbytes + (size_t)(unsigned)o2 + lofs);
            float2 f0 = up2(xw0.x), f1 = up2(xw0.y), f2v = up2(xw0.z), f3 = up2(xw0.w);
            float2 ps = make_float2(0.f, 0.f);
            ps = pk_fma(at2[0], pk_leaky(pk_add(f0, xr2[0])), ps);
            ps = pk_fma(at2[1], pk_leaky(pk_add(f1, xr2[1])), ps);
            ps = pk_fma(at2[2], pk_leaky(pk_add(f2v, xr2[2])), ps);
            ps = pk_fma(at2[3], pk_leaky(pk_add(f3, xr2[3])), ps);
            float p = ps.x + ps.y;
            p += __shfl_xor(p, 1);   // 4-lane head group
            p += __shfl_xor(p, 2);
            float w = __expf(p);
            den += w;
            float2 w2 = make_float2(w, w);
            acc[0] = pk_fma(w2, f0, acc[0]);
            acc[1] = pk_fma(w2, f1, acc[1]);
            acc[2] = pk_fma(w2, f2v, acc[2]);
            acc[3] = pk_fma(w2, f3, acc[3]);
            j += 8;
            v0 = v1; v1 = v2;
            xw0 = xw1; xw1 = xw2;
        }
        int par = nn & 1;
        *(float4*)&s_acc[par][g][l][0] = make_float4(acc[0].x, acc[0].y, acc[1].x, acc[1].y);
        *(float4*)&s_acc[par][g][l][4] = make_float4(acc[2].x, acc[2].y, acc[3].x, acc[3].y);
        s_den[par][g][l] = den;
        __syncthreads();
        int cl = t >> 3, cj = t & 7;
        float a = 0.f, d = 0.f;
#pragma unroll
        for (int gg = 0; gg < 8; gg++) {
            a += s_acc[par][gg][cl][cj];
            d += s_den[par][gg][cl];
        }
        float hv = a / d + cb;
        houtb[(size_t)i * HID + t] = f2b(hv);
        ssum += hv;
        ssum2 += hv * hv;
    }
    float* srep = stats + (size_t)(blockIdx.x & (REP - 1)) * 256;
    atomicAdd(&srep[t], ssum);
    atomicAdd(&srep[128 + t], ssum2);
}

// ---------------- final fc (bf16 x) ----------------
__global__ void __launch_bounds__(256) k_fc(const unsigned short* __restrict__ xb,
                                            const float* __restrict__ fc_W,
                                            const float* __restrict__ fc_b,
                                            float* __restrict__ out) {
    int t = threadIdx.x;
    int node = blockIdx.x * 4 + (t >> 6);
    int lane = t & 63;
    if (node >= NN) return;
    unsigned xu = *(const unsigned*)&xb[node * HID + lane * 2];
    float2 xv = up2(xu);
    float2 wv = *(const float2*)&fc_W[lane * 2];
    float p = xv.x * wv.x + xv.y * wv.y;
    p += __shfl_xor(p, 32);
    p += __shfl_xor(p, 16);
    p += __shfl_xor(p, 8);
    p += __shfl_xor(p, 4);
    p += __shfl_xor(p, 2);
    p += __shfl_xor(p, 1);
    if (lane == 0) out[node] = p + fc_b[0];
}

extern "C" void kernel_launch(void* const* d_in, const int* in_sizes, int n_in,
                              void* d_out, int out_size, void* d_ws, size_t ws_size,
                              hipStream_t stream) {
    const float* x_in   = (const float*)d_in[0];
    const int*   ei     = (const int*)d_in[1];
    const float* Wl     = (const float*)d_in[2];
    const float* Wr     = (const float*)d_in[3];
    const float* att    = (const float*)d_in[4];
    const float* conv_b = (const float*)d_in[5];
    const float* gn_w   = (const float*)d_in[6];
    const float* gn_b   = (const float*)d_in[7];
    const float* gn_ms  = (const float*)d_in[8];
    const float* skip_W = (const float*)d_in[9];
    const float* skip_b = (const float*)d_in[10];
    const float* fc_W   = (const float*)d_in[11];
    const float* fc_b   = (const float*)d_in[12];
    float* out = (float*)d_out;

    // workspace carve
    float* ws = (float*)d_ws;
    float* stats = ws;                              // REP * 256
    float* scoff = stats + REP * 256;               // 256
    unsigned short* xlr   = (unsigned short*)(scoff + 256);  // N*256 bf16
    unsigned short* b16X  = xlr + (size_t)NN * 256; // N*HID bf16 (residual stream)
    unsigned short* hbufb = b16X + NN * HID;        // N*HID bf16
    unsigned short* wt    = hbufb + NN * HID;       // 4*256*128
    unsigned short* st    = wt + 4 * 256 * 128;     // 128*128
    int* row_ptr = (int*)(st + 128 * 128);          // N+1
    int* bcnt    = row_ptr + NN + 1;                // NB
    int* csr_off = bcnt + NB;                       // NE (byte offsets)
    unsigned* bbuf = (unsigned*)(csr_off + NE);     // NB*BCAP

    k_prep<<<(NN * HID / 4 + 255) / 256, 256, 0, stream>>>(
        x_in, Wl, Wr, skip_W, b16X, wt, st, bcnt, stats);

    // CSR build via bucket sort
    k_bin<<<(NE + TB - 1) / TB, 256, 0, stream>>>(ei, bcnt, bbuf);
    k_bucket_csr<<<NB, 256, 0, stream>>>(bbuf, bcnt, row_ptr, csr_off);

    const int rtiles = (NN + 63) / 64;              // 782
    const int gat_blocks = (NN + NPB - 1) / NPB;    // 6250
    for (int l = 0; l < 4; l++) {
        k_gemm_dual_mfma<<<rtiles, 256, 0, stream>>>(
            b16X, wt + (size_t)l * 256 * 128, xlr);
        k_gat_node<<<gat_blocks, 128, 0, stream>>>(
            xlr, att + l * HID, conv_b + l * HID, row_ptr, csr_off,
            hbufb, stats);
        k_finalize<<<1, 1024, 0, stream>>>(stats, gn_w + l * HID,
                                           gn_b + l * HID, gn_ms + l * HID, scoff);
        k_gemm_skip_mfma<<<dim3(rtiles, 2), 256, 0, stream>>>(
            hbufb, scoff, st, skip_b, b16X);
    }
    k_fc<<<(NN + 3) / 4, 256, 0, stream>>>(b16X, fc_W, fc_b, out);
}

// Round 15
// 587.586 us; speedup vs baseline: 2.0889x; 1.0442x over previous
//
#include <hip/hip_runtime.h>
#include <hip/hip_bf16.h>

#define NN 50000
#define EE 800000
#define NE 850000       // edges + self-loops
#define HID 128
#define NEG_SLOPE 0.2f
#define EPSN 1e-5f
#define NB 196          // buckets of 256 nodes
#define BCAP 6144       // bucket capacity (expected 4352 +- 64)
#define TB 4096         // edges per k_bin block
#define REP 128         // GraphNorm stats replicas
#define NPB 8           // nodes per k_gat_node block

typedef __attribute__((ext_vector_type(8))) short bf16x8;
typedef __attribute__((ext_vector_type(4))) float f32x4;

__device__ __forceinline__ unsigned short f2b(float f) {
    unsigned u = __float_as_uint(f);
    unsigned r = (u + 0x7FFFu + ((u >> 16) & 1u)) >> 16;
    return (unsigned short)r;
}
__device__ __forceinline__ float b2f(unsigned short u) {
    return __uint_as_float(((unsigned)u) << 16);
}
__device__ __forceinline__ float2 up2(unsigned u) {
    return make_float2(__uint_as_float(u << 16),
                       __uint_as_float(u & 0xFFFF0000u));
}
__device__ __forceinline__ float2 pk_fma(float2 a, float2 b, float2 c) {
    return make_float2(fmaf(a.x, b.x, c.x), fmaf(a.y, b.y, c.y));
}
__device__ __forceinline__ float2 pk_add(float2 a, float2 b) {
    return make_float2(a.x + b.x, a.y + b.y);
}
__device__ __forceinline__ float2 pk_leaky(float2 v) {
    return make_float2(fmaxf(v.x, NEG_SLOPE * v.x), fmaxf(v.y, NEG_SLOPE * v.y));
}

// ---------------- prep: W->bf16^T, x->bf16, zero bcnt + stats ----------------
__global__ void k_prep(const float* __restrict__ x, const float* __restrict__ Wl,
                       const float* __restrict__ Wr, const float* __restrict__ skip_W,
                       unsigned short* __restrict__ xb, unsigned short* __restrict__ wt,
                       unsigned short* __restrict__ st, int* __restrict__ bcnt,
                       float* __restrict__ stats) {
    int i = blockIdx.x * blockDim.x + threadIdx.x;
    if (i < NN * HID / 4) {
        float4 v = *(const float4*)&x[i * 4];
        ushort4 o = {f2b(v.x), f2b(v.y), f2b(v.z), f2b(v.w)};
        *(ushort4*)&xb[i * 4] = o;
    }
    if (i < NB) bcnt[i] = 0;
    if (i < REP * 256) stats[i] = 0.f;
    if (i < 4 * 256 * 128) {
        int l = i >> 15, rem = i & 32767;
        int c = rem >> 7, k = rem & 127;
        float v = (c < 128) ? Wl[l * 16384 + k * 128 + c]
                            : Wr[l * 16384 + k * 128 + (c - 128)];
        wt[i] = f2b(v);
    } else if (i < 4 * 256 * 128 + 128 * 128) {
        int j = i - 4 * 256 * 128;
        int c = j >> 7, k = j & 127;
        st[j] = f2b(skip_W[k * 128 + c]);
    }
}

// ---------------- CSR build: bucket sort ----------------
__global__ void __launch_bounds__(256) k_bin(const int* __restrict__ ei,
                                             int* __restrict__ bcnt,
                                             unsigned* __restrict__ bbuf) {
    __shared__ int hist[NB];
    __shared__ int gbase[NB];
    int t = threadIdx.x;
    for (int b = t; b < NB; b += 256) hist[b] = 0;
    __syncthreads();
    int e0 = blockIdx.x * TB;
    unsigned ent[16];
    int bkt[16];
#pragma unroll
    for (int k = 0; k < 16; k++) {
        int e = e0 + k * 256 + t;
        if (e < NE) {
            int src, dst;
            if (e < EE) { src = ei[e]; dst = ei[EE + e]; }
            else        { src = e - EE; dst = src; }
            int b = dst >> 8;
            ent[k] = ((unsigned)(dst & 255) << 17) | (unsigned)src;
            bkt[k] = b;
            atomicAdd(&hist[b], 1);
        } else bkt[k] = -1;
    }
    __syncthreads();
    for (int b = t; b < NB; b += 256) {
        int c = hist[b];
        gbase[b] = (c > 0) ? atomicAdd(&bcnt[b], c) : 0;
        hist[b] = 0;
    }
    __syncthreads();
#pragma unroll
    for (int k = 0; k < 16; k++) {
        int b = bkt[k];
        if (b >= 0) {
            int pos = gbase[b] + atomicAdd(&hist[b], 1);
            if (pos < BCAP) bbuf[(size_t)b * BCAP + pos] = ent[k];
        }
    }
}

// Per-bucket CSR with inline prefix scan; csr stores BYTE offsets (src*512).
__global__ void __launch_bounds__(256) k_bucket_csr(
    const unsigned* __restrict__ bbuf, const int* __restrict__ bcnt,
    int* __restrict__ row_ptr, int* __restrict__ csr_off) {
    __shared__ unsigned se[BCAP];
    __shared__ int pre[256];
    __shared__ int hist[256], scn[256], exs[256], cur[256];
    int b = blockIdx.x, t = threadIdx.x;
    int bv = (t < NB) ? bcnt[t] : 0;
    pre[t] = bv;
    __syncthreads();
    for (int o = 1; o < 256; o <<= 1) {
        int u = (t >= o) ? pre[t - o] : 0;
        __syncthreads();
        pre[t] += u;
        __syncthreads();
    }
    int cntb = bcnt[b];
    int base = pre[b] - cntb;          // exclusive prefix
    int cnt = min(cntb, BCAP);
    hist[t] = 0;
    cur[t] = 0;
    __syncthreads();
    for (int j = t; j < cnt; j += 256) {
        unsigned e = bbuf[(size_t)b * BCAP + j];
        se[j] = e;
        atomicAdd(&hist[e >> 17], 1);
    }
    __syncthreads();
    int v = hist[t];
    scn[t] = v;
    __syncthreads();
    for (int o = 1; o < 256; o <<= 1) {
        int u = (t >= o) ? scn[t - o] : 0;
        __syncthreads();
        scn[t] += u;
        __syncthreads();
    }
    int ex = scn[t] - v;
    exs[t] = ex;
    int node = b * 256 + t;
    if (node < NN) row_ptr[node] = base + ex;
    if (b == NB - 1 && t == 0) row_ptr[NN] = NE;
    __syncthreads();
    for (int j = t; j < cnt; j += 256) {
        unsigned e = se[j];
        int dl = e >> 17;
        int p = exs[dl] + atomicAdd(&cur[dl], 1);
        csr_off[base + p] = (int)((e & 0x1FFFFu) << 9);   // src * 512 bytes
    }
}

// ---------------- MFMA GEMM (layer 0 only): xlr = Xb @ Wcat ----------------
__global__ void __launch_bounds__(256) k_gemm_dual_mfma(
    const unsigned short* __restrict__ Xb, const unsigned short* __restrict__ WT,
    unsigned short* __restrict__ C) {
    int w = threadIdx.x >> 6, lane = threadIdx.x & 63;
    int quad = lane >> 4, l16 = lane & 15;
    int r0 = blockIdx.x * 64 + w * 16;
    int lrow = r0 + l16; if (lrow >= NN) lrow = NN - 1;
    const unsigned short* arow = Xb + (size_t)lrow * 128 + quad * 8;
    bf16x8 a[4];
#pragma unroll
    for (int ks = 0; ks < 4; ks++) a[ks] = *(const bf16x8*)(arow + ks * 32);
    f32x4 acc[16];
#pragma unroll
    for (int ct = 0; ct < 16; ct++) acc[ct] = (f32x4){0, 0, 0, 0};
#pragma unroll
    for (int ct = 0; ct < 16; ct++) {
        const unsigned short* bbase = WT + (size_t)(ct * 16 + l16) * 128 + quad * 8;
#pragma unroll
        for (int ks = 0; ks < 4; ks++) {
            bf16x8 b = *(const bf16x8*)(bbase + ks * 32);
            acc[ct] = __builtin_amdgcn_mfma_f32_16x16x32_bf16(a[ks], b, acc[ct], 0, 0, 0);
        }
    }
    int sr = r0 + quad * 4;
#pragma unroll
    for (int ct = 0; ct < 16; ct++) {
#pragma unroll
        for (int r = 0; r < 4; r++) {
            int rr = sr + r;
            if (rr < NN) C[(size_t)rr * 256 + ct * 16 + l16] = f2b(acc[ct][r]);
        }
    }
}

// ---------------- reduce stats replicas -> scale/offset; re-zero ----------------
__global__ void __launch_bounds__(1024) k_finalize(
    float* __restrict__ stats, const float* __restrict__ gn_w,
    const float* __restrict__ gn_b, const float* __restrict__ gn_ms,
    float* __restrict__ scoff) {
    __shared__ float red[1024];
    __shared__ float tot[256];
    int t = threadIdx.x;
    int col = t & 255, part = t >> 8;
    float s = 0.f;
    for (int r = part * (REP / 4); r < (part + 1) * (REP / 4); r++)
        s += stats[(size_t)r * 256 + col];
    red[t] = s;
    __syncthreads();
    if (part == 0) tot[col] = red[col] + red[col + 256] + red[col + 512] + red[col + 768];
    __syncthreads();
    for (int j = t; j < REP * 256; j += 1024) stats[j] = 0.f;
    if (t < 128) {
        const float invN = 1.0f / (float)NN;
        float mean = tot[t] * invN;
        float ex2 = tot[128 + t] * invN;
        float ms = gn_ms[t];
        float var = ex2 - (2.f * ms - ms * ms) * mean * mean;
        float wsc = gn_w[t] * rsqrtf(var + EPSN);
        scoff[t] = wsc;
        scoff[128 + t] = gn_b[t] - wsc * ms * mean;
    }
}

// ---------------- skip-GEMM core: acc[8] = ELU(scale*h+off) @ skipW ----------------
__device__ __forceinline__ void skip_core(
    const unsigned short* __restrict__ hbufb, const float* __restrict__ scoff,
    const unsigned short* __restrict__ ST, int lrow, int quad, int l16,
    f32x4 (&acc)[8]) {
    const unsigned short* hrow = hbufb + (size_t)lrow * 128 + quad * 8;
#pragma unroll
    for (int ct = 0; ct < 8; ct++) acc[ct] = (f32x4){0, 0, 0, 0};
#pragma unroll
    for (int ks = 0; ks < 4; ks++) {
        int k0 = ks * 32;
        int kc = quad * 8 + k0;
        uint4 hw = *(const uint4*)(hrow + k0);
        float2 h01 = up2(hw.x), h23 = up2(hw.y), h45 = up2(hw.z), h67 = up2(hw.w);
        float4 sc0 = *(const float4*)(scoff + kc);
        float4 sc1 = *(const float4*)(scoff + kc + 4);
        float4 of0 = *(const float4*)(scoff + 128 + kc);
        float4 of1 = *(const float4*)(scoff + 128 + kc + 4);
        float e[8];
        e[0] = fmaf(sc0.x, h01.x, of0.x); e[1] = fmaf(sc0.y, h01.y, of0.y);
        e[2] = fmaf(sc0.z, h23.x, of0.z); e[3] = fmaf(sc0.w, h23.y, of0.w);
        e[4] = fmaf(sc1.x, h45.x, of1.x); e[5] = fmaf(sc1.y, h45.y, of1.y);
        e[6] = fmaf(sc1.z, h67.x, of1.z); e[7] = fmaf(sc1.w, h67.y, of1.w);
        bf16x8 af;
#pragma unroll
        for (int j = 0; j < 8; j++) {
            float v = e[j];
            v = (v > 0.f) ? v : (__expf(v) - 1.f);
            af[j] = (short)f2b(v);
        }
#pragma unroll
        for (int ct = 0; ct < 8; ct++) {
            bf16x8 b = *(const bf16x8*)(ST + (size_t)(ct * 16 + l16) * 128 + quad * 8 + k0);
            acc[ct] = __builtin_amdgcn_mfma_f32_16x16x32_bf16(af, b, acc[ct], 0, 0, 0);
        }
    }
}

// ---------------- fused skip + next-layer dual GEMM ----------------
// X += ELU(norm(h))@skipW + sb  (staged in LDS, coalesced Xb16 I/O), then
// xlr = X @ WTnext via MFMA (A-frags from LDS), coalesced xlr stores.
__global__ void __launch_bounds__(256) k_skip_dual(
    const unsigned short* __restrict__ hbufb, const float* __restrict__ scoff,
    const unsigned short* __restrict__ ST, const float* __restrict__ skip_b,
    unsigned short* __restrict__ Xb16,
    const unsigned short* __restrict__ WTnext, unsigned short* __restrict__ xlr) {
    __shared__ unsigned short tileX[64][136];      // block-wide new X (bf16)
    __shared__ unsigned short tileC[4][16][264];   // per-wave xlr staging
    int t = threadIdx.x;
    int w = t >> 6, lane = t & 63;
    int quad = lane >> 4, l16 = lane & 15;
    int r0b = blockIdx.x * 64;
    int r0 = r0b + w * 16;
    int lrow = r0 + l16; if (lrow >= NN) lrow = NN - 1;
    // stage old X rows (coalesced)
#pragma unroll
    for (int it = 0; it < 4; it++) {
        int idx = it * 256 + t;             // 1024 uint4s = 64 rows x 16
        int row = idx >> 4;
        int c8 = (idx & 15) * 8;
        int rr = r0b + row;
        uint4 v = (rr < NN) ? *(const uint4*)&Xb16[(size_t)rr * 128 + c8]
                            : (uint4){0, 0, 0, 0};
        *(uint4*)&tileX[row][c8] = v;
    }
    f32x4 acc[8];
    skip_core(hbufb, scoff, ST, lrow, quad, l16, acc);
    __syncthreads();    // tileX staged
    // epilogue: v = oldX + acc + sb -> tileX (bf16)
#pragma unroll
    for (int ct = 0; ct < 8; ct++) {
        int c = ct * 16 + l16;
        float sb = skip_b[c];
#pragma unroll
        for (int r = 0; r < 4; r++) {
            int wrow = w * 16 + quad * 4 + r;
            float v = b2f(tileX[wrow][c]) + acc[ct][r] + sb;
            tileX[wrow][c] = f2b(v);
        }
    }
    __syncthreads();    // new X ready
    // store new Xb16 (coalesced)
#pragma unroll
    for (int it = 0; it < 4; it++) {
        int idx = it * 256 + t;
        int row = idx >> 4;
        int c8 = (idx & 15) * 8;
        int rr = r0b + row;
        if (rr < NN) *(uint4*)&Xb16[(size_t)rr * 128 + c8] = *(const uint4*)&tileX[row][c8];
    }
    // next-layer dual: A-frags from tileX
    int wrowA = w * 16 + l16;
    bf16x8 a[4];
#pragma unroll
    for (int ks = 0; ks < 4; ks++)
        a[ks] = *(const bf16x8*)&tileX[wrowA][quad * 8 + ks * 32];
    f32x4 dacc[16];
#pragma unroll
    for (int ct = 0; ct < 16; ct++) dacc[ct] = (f32x4){0, 0, 0, 0};
#pragma unroll
    for (int ct = 0; ct < 16; ct++) {
        const unsigned short* bbase = WTnext + (size_t)(ct * 16 + l16) * 128 + quad * 8;
#pragma unroll
        for (int ks = 0; ks < 4; ks++) {
            bf16x8 b = *(const bf16x8*)(bbase + ks * 32);
            dacc[ct] = __builtin_amdgcn_mfma_f32_16x16x32_bf16(a[ks], b, dacc[ct], 0, 0, 0);
        }
    }
#pragma unroll
    for (int ct = 0; ct < 16; ct++) {
#pragma unroll
        for (int r = 0; r < 4; r++)
            tileC[w][quad * 4 + r][ct * 16 + l16] = f2b(dacc[ct][r]);
    }
    __syncthreads();
    // coalesced xlr stores: per wave 16 rows x 256 cols
#pragma unroll
    for (int it = 0; it < 8; it++) {
        int idx = it * 64 + lane;           // 512 uint4s = 16 rows x 32
        int row = idx >> 5;
        int c8 = (idx & 31) * 8;
        int rr = r0 + row;
        if (rr < NN) *(uint4*)&xlr[(size_t)rr * 256 + c8] = *(const uint4*)&tileC[w][row][c8];
    }
}

// ---------------- fused skip + final fc (last layer) ----------------
__global__ void __launch_bounds__(256) k_skip_fc(
    const unsigned short* __restrict__ hbufb, const float* __restrict__ scoff,
    const unsigned short* __restrict__ ST, const float* __restrict__ skip_b,
    const unsigned short* __restrict__ Xb16,
    const float* __restrict__ fc_W, const float* __restrict__ fc_b,
    float* __restrict__ out) {
    __shared__ unsigned short tileX[64][136];
    int t = threadIdx.x;
    int w = t >> 6, lane = t & 63;
    int quad = lane >> 4, l16 = lane & 15;
    int r0b = blockIdx.x * 64;
    int r0 = r0b + w * 16;
    int lrow = r0 + l16; if (lrow >= NN) lrow = NN - 1;
#pragma unroll
    for (int it = 0; it < 4; it++) {
        int idx = it * 256 + t;
        int row = idx >> 4;
        int c8 = (idx & 15) * 8;
        int rr = r0b + row;
        uint4 v = (rr < NN) ? *(const uint4*)&Xb16[(size_t)rr * 128 + c8]
                            : (uint4){0, 0, 0, 0};
        *(uint4*)&tileX[row][c8] = v;
    }
    f32x4 acc[8];
    skip_core(hbufb, scoff, ST, lrow, quad, l16, acc);
    __syncthreads();
    float p[4] = {0.f, 0.f, 0.f, 0.f};
#pragma unroll
    for (int ct = 0; ct < 8; ct++) {
        int c = ct * 16 + l16;
        float sb = skip_b[c];
        float fw = fc_W[c];
#pragma unroll
        for (int r = 0; r < 4; r++) {
            int wrow = w * 16 + quad * 4 + r;
            float v = b2f(tileX[wrow][c]) + acc[ct][r] + sb;
            p[r] = fmaf(v, fw, p[r]);
        }
    }
    // reduce over the 16 lanes (l16) sharing the same 4 rows
#pragma unroll
    for (int r = 0; r < 4; r++) {
        p[r] += __shfl_xor(p[r], 1);
        p[r] += __shfl_xor(p[r], 2);
        p[r] += __shfl_xor(p[r], 4);
        p[r] += __shfl_xor(p[r], 8);
    }
    if (l16 == 0) {
        float fb = fc_b[0];
#pragma unroll
        for (int r = 0; r < 4; r++) {
            int rr = r0 + quad * 4 + r;
            if (rr < NN) out[rr] = p[r] + fb;
        }
    }
}

// ---------------- fused GATv2 (R10 structure): 8 slots stride one node ----------------
__global__ void __launch_bounds__(128) k_gat_node(
    const unsigned short* __restrict__ xlr,
    const float* __restrict__ att, const float* __restrict__ conv_b,
    const int* __restrict__ row_ptr, const int* __restrict__ csr_off,
    unsigned short* __restrict__ houtb, float* __restrict__ stats) {
    int t = threadIdx.x;
    int g = t >> 4;          // slot 0..7
    int l = t & 15;          // lane in slot: owns channels 8l..8l+7
    const char* xbytes = (const char*)xlr;
    int lofs = 16 * l;
    float2 at2[4];
    {
        float4 a0 = *(const float4*)&att[8 * l];
        float4 a1 = *(const float4*)&att[8 * l + 4];
        at2[0] = make_float2(a0.x, a0.y); at2[1] = make_float2(a0.z, a0.w);
        at2[2] = make_float2(a1.x, a1.y); at2[3] = make_float2(a1.z, a1.w);
    }
    float cb = conv_b[t];
    int i0 = blockIdx.x * NPB;
    int rp[NPB + 1];
#pragma unroll
    for (int k = 0; k <= NPB; k++) rp[k] = row_ptr[i0 + k];   // wave-uniform -> scalar
    __shared__ float s_acc[2][8][16][12];
    __shared__ float s_den[2][8][16];
    float ssum = 0.f, ssum2 = 0.f;
    uint4 xr_next = *(const uint4*)(xbytes + (size_t)i0 * 512 + 256 + lofs);
    for (int nn = 0; nn < NPB; nn++) {
        int i = i0 + nn;
        uint4 xr_raw = xr_next;
        if (nn + 1 < NPB)
            xr_next = *(const uint4*)(xbytes + (size_t)(i + 1) * 512 + 256 + lofs);
        float2 xr2[4];
        xr2[0] = up2(xr_raw.x); xr2[1] = up2(xr_raw.y);
        xr2[2] = up2(xr_raw.z); xr2[3] = up2(xr_raw.w);
        int start = rp[nn], end = rp[nn + 1];
        float den = 0.f;
        float2 acc[4];
#pragma unroll
        for (int k = 0; k < 4; k++) acc[k] = make_float2(0.f, 0.f);
        int j = start + g;
        bool v0 = j < end;
        int o0 = v0 ? csr_off[j] : 0;
        bool v1 = (j + 8) < end;
        int o1 = v1 ? csr_off[j + 8] : 0;
        uint4 xw0 = {0,0,0,0}, xw1 = {0,0,0,0};
        if (v0) xw0 = *(const uint4*)(xbytes + (size_t)(unsigned)o0 + lofs);
        if (v1) xw1 = *(const uint4*)(xbytes + (size_t)(unsigned)o1 + lofs);
        while (v0) {
            bool v2 = (j + 16) < end;
            int o2 = v2 ? csr_off[j + 16] : 0;
            uint4 xw2 = {0,0,0,0};
            if (v2) xw2 = *(const uint4*)(xbytes + (size_t)(unsigned)o2 + lofs);
            float2 f0 = up2(xw0.x), f1 = up2(xw0.y), f2v = up2(xw0.z), f3 = up2(xw0.w);
            float2 ps = make_float2(0.f, 0.f);
            ps = pk_fma(at2[0], pk_leaky(pk_add(f0, xr2[0])), ps);
            ps = pk_fma(at2[1], pk_leaky(pk_add(f1, xr2[1])), ps);
            ps = pk_fma(at2[2], pk_leaky(pk_add(f2v, xr2[2])), ps);
            ps = pk_fma(at2[3], pk_leaky(pk_add(f3, xr2[3])), ps);
            float p = ps.x + ps.y;
            p += __shfl_xor(p, 1);   // 4-lane head group
            p += __shfl_xor(p, 2);
            float w = __expf(p);
            den += w;
            float2 w2 = make_float2(w, w);
            acc[0] = pk_fma(w2, f0, acc[0]);
            acc[1] = pk_fma(w2, f1, acc[1]);
            acc[2] = pk_fma(w2, f2v, acc[2]);
            acc[3] = pk_fma(w2, f3, acc[3]);
            j += 8;
            v0 = v1; v1 = v2;
            xw0 = xw1; xw1 = xw2;
        }
        int par = nn & 1;
        *(float4*)&s_acc[par][g][l][0] = make_float4(acc[0].x, acc[0].y, acc[1].x, acc[1].y);
        *(float4*)&s_acc[par][g][l][4] = make_float4(acc[2].x, acc[2].y, acc[3].x, acc[3].y);
        s_den[par][g][l] = den;
        __syncthreads();
        int cl = t >> 3, cj = t & 7;
        float a = 0.f, d = 0.f;
#pragma unroll
        for (int gg = 0; gg < 8; gg++) {
            a += s_acc[par][gg][cl][cj];
            d += s_den[par][gg][cl];
        }
        float hv = a / d + cb;
        houtb[(size_t)i * HID + t] = f2b(hv);
        ssum += hv;
        ssum2 += hv * hv;
    }
    float* srep = stats + (size_t)(blockIdx.x & (REP - 1)) * 256;
    atomicAdd(&srep[t], ssum);
    atomicAdd(&srep[128 + t], ssum2);
}

extern "C" void kernel_launch(void* const* d_in, const int* in_sizes, int n_in,
                              void* d_out, int out_size, void* d_ws, size_t ws_size,
                              hipStream_t stream) {
    const float* x_in   = (const float*)d_in[0];
    const int*   ei     = (const int*)d_in[1];
    const float* Wl     = (const float*)d_in[2];
    const float* Wr     = (const float*)d_in[3];
    const float* att    = (const float*)d_in[4];
    const float* conv_b = (const float*)d_in[5];
    const float* gn_w   = (const float*)d_in[6];
    const float* gn_b   = (const float*)d_in[7];
    const float* gn_ms  = (const float*)d_in[8];
    const float* skip_W = (const float*)d_in[9];
    const float* skip_b = (const float*)d_in[10];
    const float* fc_W   = (const float*)d_in[11];
    const float* fc_b   = (const float*)d_in[12];
    float* out = (float*)d_out;

    // workspace carve
    float* ws = (float*)d_ws;
    float* stats = ws;                              // REP * 256
    float* scoff = stats + REP * 256;               // 256
    unsigned short* xlr   = (unsigned short*)(scoff + 256);  // N*256 bf16
    unsigned short* b16X  = xlr + (size_t)NN * 256; // N*HID bf16 (residual stream)
    unsigned short* hbufb = b16X + NN * HID;        // N*HID bf16
    unsigned short* wt    = hbufb + NN * HID;       // 4*256*128
    unsigned short* st    = wt + 4 * 256 * 128;     // 128*128
    int* row_ptr = (int*)(st + 128 * 128);          // N+1
    int* bcnt    = row_ptr + NN + 1;                // NB
    int* csr_off = bcnt + NB;                       // NE (byte offsets)
    unsigned* bbuf = (unsigned*)(csr_off + NE);     // NB*BCAP

    k_prep<<<(NN * HID / 4 + 255) / 256, 256, 0, stream>>>(
        x_in, Wl, Wr, skip_W, b16X, wt, st, bcnt, stats);

    // CSR build via bucket sort
    k_bin<<<(NE + TB - 1) / TB, 256, 0, stream>>>(ei, bcnt, bbuf);
    k_bucket_csr<<<NB, 256, 0, stream>>>(bbuf, bcnt, row_ptr, csr_off);

    const int rtiles = (NN + 63) / 64;              // 782
    const int gat_blocks = (NN + NPB - 1) / NPB;    // 6250
    k_gemm_dual_mfma<<<rtiles, 256, 0, stream>>>(b16X, wt, xlr);
    for (int l = 0; l < 4; l++) {
        k_gat_node<<<gat_blocks, 128, 0, stream>>>(
            xlr, att + l * HID, conv_b + l * HID, row_ptr, csr_off,
            hbufb, stats);
        k_finalize<<<1, 1024, 0, stream>>>(stats, gn_w + l * HID,
                                           gn_b + l * HID, gn_ms + l * HID, scoff);
        if (l < 3) {
            k_skip_dual<<<rtiles, 256, 0, stream>>>(
                hbufb, scoff, st, skip_b, b16X,
                wt + (size_t)(l + 1) * 256 * 128, xlr);
        } else {
            k_skip_fc<<<rtiles, 256, 0, stream>>>(
                hbufb, scoff, st, skip_b, b16X, fc_W, fc_b, out);
        }
    }
}